// Round 17
// baseline (180.906 us; speedup 1.0000x reference)
//
#include <hip/hip_runtime.h>
#include <hip/hip_bf16.h>

typedef unsigned short u16;
typedef __attribute__((ext_vector_type(8))) short short8;
typedef __attribute__((ext_vector_type(4))) float f32x4;
typedef __attribute__((ext_vector_type(4))) unsigned short us4;

#define DEV __device__ __forceinline__

DEV float bf2f(u16 u){ unsigned v = ((unsigned)u) << 16; float f; __builtin_memcpy(&f, &v, 4); return f; }
DEV u16 f2bf(float f){ __hip_bfloat16 h = __float2bfloat16(f); u16 u; __builtin_memcpy(&u, &h, 2); return u; }
DEV u16 f2bf_fast(float f){ unsigned u; __builtin_memcpy(&u, &f, 4); return (u16)((u + 0x8000u) >> 16); }

DEV void gload_lds16(const void* g, void* l){
  __builtin_amdgcn_global_load_lds((const __attribute__((address_space(1))) void*)g,
                                   (__attribute__((address_space(3))) void*)l, 16, 0, 0);
}

#define INV_LN2 1.4426950408889634f

DEV bool detect_inline(const unsigned* __restrict__ xw){
  int cnt = 0;
#pragma unroll
  for (int i = 0; i < 64; ++i){
    unsigned e = (xw[i] >> 7) & 0xFFu;
    cnt += (e >= 0x68u && e <= 0x8Fu) ? 1 : 0;
  }
  return cnt >= 32;
}

// ---------------- fused flag-aware convert of small inputs ----------------
struct ConvArgs {
  const void* src[12];
  u16* dst[12];
  int cum[13];
};
__global__ void convert_all(ConvArgs a, const unsigned* __restrict__ xw, int* __restrict__ flag){
  bool isbf = detect_inline(xw);
  if (blockIdx.x == 0 && threadIdx.x == 0) *flag = isbf ? 1 : 0;
  int total = a.cum[12];
  for (int g = blockIdx.x * 256 + threadIdx.x; g < total; g += gridDim.x * 256){
    int s = 0;
    while (g >= a.cum[s + 1]) ++s;
    int i = g - a.cum[s];
    if (isbf){
      ((us4*)a.dst[s])[i] = ((const us4*)a.src[s])[i];
    } else {
      f32x4 v = ((const f32x4*)a.src[s])[i];
      us4 o;
#pragma unroll
      for (int j = 0; j < 4; ++j) o[j] = f2bf(v[j]);
      ((us4*)a.dst[s])[i] = o;
    }
  }
}

// ---------------- fused flag-aware 32x32 tiled transposes (4 weights) ----------------
struct TransArgs {
  const void* src[4];
  u16* dst[4];
  int R[4], C[4];
  int cumb[5];
};
__global__ void transpose_all(TransArgs a, const unsigned* __restrict__ xw){
  __shared__ u16 tl[32][33];
  bool isbf = detect_inline(xw);
  int b = blockIdx.x;
  int s = 0;
  while (b >= a.cumb[s + 1]) ++s;
  int lb = b - a.cumb[s];
  const void* in = a.src[s];
  u16* out = a.dst[s];
  int R = a.R[s], Cc = a.C[s];
  int ntc = Cc >> 5;
  int br = lb / ntc, bc = lb % ntc;
  int t = threadIdx.x;
#pragma unroll
  for (int i = 0; i < 4; ++i){
    int r = (t >> 5) + i * 8, c = t & 31;
    size_t idx = (size_t)(br * 32 + r) * Cc + bc * 32 + c;
    tl[r][c] = isbf ? ((const u16*)in)[idx] : f2bf(((const float*)in)[idx]);
  }
  __syncthreads();
#pragma unroll
  for (int i = 0; i < 4; ++i){
    int c = (t >> 5) + i * 8, r = t & 31;
    out[(size_t)(bc * 32 + c) * R + br * 32 + r] = tl[r][c];
  }
}

// ---------------- LN1 v2: vectorized raw reads, 16-l tiles ----------------
__global__ void ln1_pos_kernel(const void* __restrict__ xr, const void* __restrict__ posr,
                               const u16* __restrict__ g, const u16* __restrict__ b,
                               u16* __restrict__ xf, int n0){
  __shared__ u16 xs[384 * 20];
  __shared__ float ps_[64][16], pq_[64][16];
  __shared__ float mls[16], rls[16];
  bool isbf = detect_inline((const unsigned*)xr);
  const int tid = threadIdx.x;
  const int ln_ = blockIdx.x >> 6;
  const int n = n0 + ln_;
  const int l0 = (blockIdx.x & 63) << 4;
  const int cs = tid >> 2;
  const int lq = (tid & 3) << 2;
  float s[4] = {0.f, 0.f, 0.f, 0.f}, sq[4] = {0.f, 0.f, 0.f, 0.f};
#pragma unroll
  for (int it = 0; it < 6; ++it){
    int c = cs + it * 64;
    size_t base = (size_t)(n * 384 + c) * 1024 + l0 + lq;
    float v[4];
    if (isbf){
      us4 u = *(const us4*)((const u16*)xr + base);
#pragma unroll
      for (int i = 0; i < 4; ++i) v[i] = bf2f(u[i]);
    } else {
      f32x4 f = *(const f32x4*)((const float*)xr + base);
#pragma unroll
      for (int i = 0; i < 4; ++i) v[i] = f[i];
    }
    us4 o;
#pragma unroll
    for (int i = 0; i < 4; ++i){
      s[i] += v[i]; sq[i] += v[i] * v[i];
      o[i] = f2bf_fast(v[i]);
    }
    *(us4*)&xs[c * 20 + lq] = o;
  }
#pragma unroll
  for (int i = 0; i < 4; ++i){ ps_[cs][lq + i] = s[i]; pq_[cs][lq + i] = sq[i]; }
  __syncthreads();
  for (int st = 32; st >= 1; st >>= 1){
    if (cs < st){
#pragma unroll
      for (int i = 0; i < 4; ++i){
        ps_[cs][lq + i] += ps_[cs + st][lq + i];
        pq_[cs][lq + i] += pq_[cs + st][lq + i];
      }
    }
    __syncthreads();
  }
  if (tid < 16){
    float mean = ps_[0][tid] * (1.f / 384.f);
    float var = pq_[0][tid] * (1.f / 384.f) - mean * mean;
    mls[tid] = mean; rls[tid] = rsqrtf(fmaxf(var, 0.f) + 1e-5f);
  }
  __syncthreads();
  for (int idx = tid; idx < 384 * 16; idx += 256){
    int c = idx % 384, l = idx / 384;
    size_t pidx = (size_t)(l0 + l) * 384 + c;
    float pv = isbf ? bf2f(((const u16*)posr)[pidx]) : ((const float*)posr)[pidx];
    float v = (bf2f(xs[c * 20 + l]) - mls[l]) * rls[l] * bf2f(g[c]) + bf2f(b[c]) + pv;
    xf[(size_t)(ln_ * 1024 + l0 + l) * 384 + c] = f2bf_fast(v);
  }
}

// ---------------- rowwise LN over last dim of [rows][384] ----------------
__global__ void ln_row(const u16* __restrict__ in, const u16* __restrict__ g,
                       const u16* __restrict__ b, u16* __restrict__ out){
  int w = threadIdx.x >> 6, lane = threadIdx.x & 63;
  size_t row = (size_t)blockIdx.x * 4 + w;
  const u16* r = in + row * 384;
  float v[6]; float s = 0.f, sq = 0.f;
#pragma unroll
  for (int i = 0; i < 6; ++i){ v[i] = bf2f(r[lane + i * 64]); s += v[i]; sq += v[i] * v[i]; }
#pragma unroll
  for (int m = 1; m < 64; m <<= 1){ s += __shfl_xor(s, m); sq += __shfl_xor(sq, m); }
  float mean = s * (1.f / 384.f);
  float var = sq * (1.f / 384.f) - mean * mean;
  float rv = rsqrtf(fmaxf(var, 0.f) + 1e-5f);
#pragma unroll
  for (int i = 0; i < 6; ++i){
    int c = lane + i * 64;
    out[row * 384 + c] = f2bf_fast((v[i] - mean) * rv * bf2f(g[c]) + bf2f(b[c]));
  }
}

// ====== (MF*32)x(NF*32) MFMA GEMM, 2-phase double-buffered LDS ======
template<int MODE, int NF, int MF>
__global__ void gemm128(const u16* __restrict__ A, const u16* __restrict__ BT,
                        const u16* __restrict__ bias, void* __restrict__ Co,
                        const void* __restrict__ resid, int M, int K, int Nn, int row0,
                        const int* __restrict__ oflag, u16* __restrict__ vt){
  (void)M;
  __shared__ u16 lsA[2][MF * 32 * 32];
  __shared__ u16 lsB[2][NF * 32 * 32];
  const int BM = MF * 32, BN = NF * 32;
  const int ntN = Nn / BN;
  int bid = blockIdx.x;
  {
    int nwg = gridDim.x;
    if ((nwg & 7) == 0){ int per = nwg >> 3; bid = (bid & 7) * per + (bid >> 3); }
  }
  const int bm = bid / ntN;
  const int bn = bid % ntN;
  const int tid = threadIdx.x;
  const int lane = tid & 63;
  const int w = tid >> 6;
  const int wr = w >> 1, wc = w & 1;
  const int lr = lane >> 2;
  const int lcb = (lane & 3) << 4;
  const char* Ab = (const char*)(A + (size_t)bm * BM * K);
  const char* Bb = (const char*)(BT + (size_t)bn * BN * K);
  bool robf = false;
  if (MODE == 1 || MODE == 3) robf = (*oflag != 0);

  auto stage = [&](int buf, int k0){
#pragma unroll
    for (int ch = w; ch < 2 * MF; ch += 4){
      int row = ch * 16 + lr;
      gload_lds16(Ab + ((size_t)row * K + k0) * 2 + lcb, &lsA[buf][ch * 512]);
    }
#pragma unroll
    for (int ch = w; ch < 2 * NF; ch += 4){
      int row = ch * 16 + lr;
      gload_lds16(Bb + ((size_t)row * K + k0) * 2 + lcb, &lsB[buf][ch * 512]);
    }
  };

  f32x4 zero4 = {0.f, 0.f, 0.f, 0.f};
  f32x4 acc[MF][NF];
#pragma unroll
  for (int m = 0; m < MF; ++m)
#pragma unroll
    for (int nn = 0; nn < NF; ++nn) acc[m][nn] = zero4;
  const int kk = (lane >> 4) << 3;

  stage(0, 0);
  __syncthreads();
  int cur = 0;
  for (int k0 = 0; k0 < K; k0 += 32){
    if (k0 + 32 < K) stage(cur ^ 1, k0 + 32);
    short8 af[MF], bfr[NF];
#pragma unroll
    for (int m = 0; m < MF; ++m)
      af[m] = *(const short8*)&lsA[cur][(wr * MF * 16 + m * 16 + (lane & 15)) * 32 + kk];
#pragma unroll
    for (int nn = 0; nn < NF; ++nn)
      bfr[nn] = *(const short8*)&lsB[cur][(wc * NF * 16 + nn * 16 + (lane & 15)) * 32 + kk];
    __builtin_amdgcn_s_setprio(1);
#pragma unroll
    for (int m = 0; m < MF; ++m)
#pragma unroll
      for (int nn = 0; nn < NF; ++nn)
        acc[m][nn] = __builtin_amdgcn_mfma_f32_16x16x32_bf16(af[m], bfr[nn], acc[m][nn], 0, 0, 0);
    __builtin_amdgcn_s_setprio(0);
    __syncthreads();
    cur ^= 1;
  }

#pragma unroll
  for (int m = 0; m < MF; ++m){
#pragma unroll
    for (int nn = 0; nn < NF; ++nn){
#pragma unroll
      for (int j = 0; j < 4; ++j){
        int row = bm * BM + wr * MF * 16 + m * 16 + ((lane >> 4) << 2) + j;
        int col = bn * BN + wc * NF * 16 + nn * 16 + (lane & 15);
        float v = acc[m][nn][j] + bf2f(bias[col]);
        if (MODE == 2){
          float y = 0.7978845608028654f * fmaf(0.044715f * v * v, v, v);
          v = v / (1.f + exp2f(-2.8853900817779268f * y));
        }
        if (MODE == 1){
          int rg = row0 + row;
          size_t ridx = ((size_t)((rg >> 10) * 384 + col)) * 1024 + (rg & 1023);
          v += robf ? bf2f(((const u16*)resid)[ridx]) : ((const float*)resid)[ridx];
          ((u16*)Co)[(size_t)row * Nn + col] = f2bf_fast(v);
        } else if (MODE == 3){
          int rg = row0 + row;
          v += bf2f(((const u16*)resid)[(size_t)rg * 384 + col]);
          size_t oidx = ((size_t)((rg >> 10) * 384 + col)) * 1024 + (rg & 1023);
          if (robf) ((u16*)Co)[oidx] = f2bf(v);
          else      ((float*)Co)[oidx] = v;
        } else if (MODE == 4){
          if (col < 768){
            ((u16*)Co)[(size_t)row * 768 + col] = f2bf_fast(v);
          } else {
            int vc = col - 768;
            int vh = vc / 48, vd = vc % 48;
            vt[((size_t)(((row >> 10) * 8 + vh) * 48 + vd)) * 1024 + (row & 1023)] = f2bf_fast(v);
          }
        } else {
          ((u16*)Co)[(size_t)row * Nn + col] = f2bf_fast(v);
        }
      }
    }
  }
}

#define AT_SCALE 0.14433756729740643f
#define AT_SCALE2 (0.14433756729740643f * 1.4426950408889634f)

// ---------------- attention v7: double-buffered K/V LDS, ONE barrier per kt ----------------
__global__ __launch_bounds__(256, 4)
void attn7_kernel(const u16* __restrict__ qk, const u16* __restrict__ vtg,
                  const u16* __restrict__ relH, const u16* __restrict__ relW,
                  u16* __restrict__ outp){
  __shared__ u16 Pt[64 * 72];
  __shared__ u16 Kt[2][64 * 72];
  __shared__ u16 Vt[2][48 * 72];
  __shared__ float rH[511], rW[511];
  const int tid = threadIdx.x, lane = tid & 63, w = tid >> 6;
  const int d = blockIdx.x;
  const int g = ((d >> 7) << 3) | (d & 7);
  const int m_ = (d >> 3) & 15;
  const int n = g >> 3;
  const int h = g & 7;
  const int q0 = m_ << 6;
  const short8 zz = {0, 0, 0, 0, 0, 0, 0, 0};

  for (int i = tid; i < 511; i += 256){
    rH[i] = bf2f(relH[i * 8 + h]) * INV_LN2;
    rW[i] = bf2f(relW[i * 8 + h]) * INV_LN2;
  }
  const size_t baseVT = ((size_t)((n * 8 + h) * 48)) * 1024;
  const int kk = (lane >> 4) << 3;

  const size_t baseQr = ((size_t)(n * 1024 + q0 + w * 16 + (lane & 15))) * 768 + h * 48;
  short8 aQ0 = *(const short8*)&qk[baseQr + kk];
  short8 aQ1 = (kk < 16) ? *(const short8*)&qk[baseQr + 32 + kk] : zz;

  short8 kr0, kr1, vr0, vr1;
  const int k0r = tid >> 3, k0c = tid & 7;
  const int k1r = (tid + 256) >> 3;
  const int v0d = tid >> 3, v0l = tid & 7;
  const int v1d = (tid + 256) >> 3;
  auto loadKV = [&](int kt1){
    int kv0 = kt1 << 6;
    size_t bK = ((size_t)(n * 1024 + kv0)) * 768 + 384 + h * 48;
    kr0 = (k0c < 6) ? *(const short8*)&qk[bK + (size_t)k0r * 768 + k0c * 8] : zz;
    kr1 = (k0c < 6) ? *(const short8*)&qk[bK + (size_t)k1r * 768 + k0c * 8] : zz;
    vr0 = *(const short8*)&vtg[baseVT + (size_t)v0d * 1024 + kv0 + v0l * 8];
    if (tid < 128) vr1 = *(const short8*)&vtg[baseVT + (size_t)v1d * 1024 + kv0 + v0l * 8];
  };
  auto writeKV = [&](int b){
    *(short8*)&Kt[b][k0r * 72 + k0c * 8] = kr0;
    *(short8*)&Kt[b][k1r * 72 + k0c * 8] = kr1;
    *(short8*)&Vt[b][v0d * 72 + v0l * 8] = vr0;
    if (tid < 128) *(short8*)&Vt[b][v1d * 72 + v0l * 8] = vr1;
  };

  loadKV(0);
  writeKV(0);
  __syncthreads();

  float lsum[4];
  f32x4 oac[3];
  f32x4 zero4 = {0.f, 0.f, 0.f, 0.f};
#pragma unroll
  for (int j = 0; j < 4; ++j) lsum[j] = 0.f;
#pragma unroll
  for (int d3 = 0; d3 < 3; ++d3) oac[d3] = zero4;

  int qh_[4];
  float rw0_[4], rw1_[4];
#pragma unroll
  for (int j = 0; j < 4; ++j){
    int qi = q0 + w * 16 + ((lane >> 4) << 2) + j;
    qh_[j] = qi >> 5;
    int qw = qi & 31;
    rw0_[j] = rW[qw - (lane & 15) + 255];
    rw1_[j] = rW[qw - (lane & 15) + 239];
  }

  int cur = 0;
  for (int kt = 0; kt < 16; ++kt){
    f32x4 sc[4];
#pragma unroll
    for (int nn = 0; nn < 4; ++nn) sc[nn] = zero4;
    __builtin_amdgcn_s_setprio(1);
#pragma unroll
    for (int nn = 0; nn < 4; ++nn){
      short8 bK0 = *(const short8*)&Kt[cur][(nn * 16 + (lane & 15)) * 72 + kk];
      sc[nn] = __builtin_amdgcn_mfma_f32_16x16x32_bf16(aQ0, bK0, sc[nn], 0, 0, 0);
      short8 bK1 = *(const short8*)&Kt[cur][(nn * 16 + (lane & 15)) * 72 + 32 + kk];
      sc[nn] = __builtin_amdgcn_mfma_f32_16x16x32_bf16(aQ1, bK1, sc[nn], 0, 0, 0);
    }
    __builtin_amdgcn_s_setprio(0);

    if (kt < 15) loadKV(kt + 1);

#pragma unroll
    for (int j = 0; j < 4; ++j){
      int ih = qh_[j] - (kt << 1) + 255;
      float rh0 = rH[ih], rh1 = rH[ih - 1];
      float e0 = exp2f(fmaf(sc[0][j], AT_SCALE2, rh0 + rw0_[j]));
      float e1 = exp2f(fmaf(sc[1][j], AT_SCALE2, rh0 + rw1_[j]));
      float e2 = exp2f(fmaf(sc[2][j], AT_SCALE2, rh1 + rw0_[j]));
      float e3 = exp2f(fmaf(sc[3][j], AT_SCALE2, rh1 + rw1_[j]));
      lsum[j] += (e0 + e1) + (e2 + e3);
      int prow = (w * 16 + ((lane >> 4) << 2) + j) * 72 + (lane & 15);
      Pt[prow]      = f2bf_fast(e0);
      Pt[prow + 16] = f2bf_fast(e1);
      Pt[prow + 32] = f2bf_fast(e2);
      Pt[prow + 48] = f2bf_fast(e3);
    }

    __builtin_amdgcn_s_setprio(1);
#pragma unroll
    for (int k0i = 0; k0i < 2; ++k0i){
      short8 aP = *(const short8*)&Pt[(w * 16 + (lane & 15)) * 72 + k0i * 32 + kk];
#pragma unroll
      for (int d3 = 0; d3 < 3; ++d3){
        short8 bV = *(const short8*)&Vt[cur][(d3 * 16 + (lane & 15)) * 72 + k0i * 32 + kk];
        oac[d3] = __builtin_amdgcn_mfma_f32_16x16x32_bf16(aP, bV, oac[d3], 0, 0, 0);
      }
    }
    __builtin_amdgcn_s_setprio(0);

    if (kt < 15){
      writeKV(cur ^ 1);      // other buffer: safe while peers still read cur
      __syncthreads();       // single barrier: next tile visible to all
      cur ^= 1;
    }
  }

#pragma unroll
  for (int j = 0; j < 4; ++j){
    float l = lsum[j];
    l += __shfl_xor(l, 1);
    l += __shfl_xor(l, 2);
    l += __shfl_xor(l, 4);
    l += __shfl_xor(l, 8);
    float rl = 1.0f / l;
    int row = q0 + w * 16 + ((lane >> 4) << 2) + j;
#pragma unroll
    for (int d3 = 0; d3 < 3; ++d3){
      int col = h * 48 + d3 * 16 + (lane & 15);
      outp[(size_t)(n * 1024 + row) * 384 + col] = f2bf_fast(oac[d3][j] * rl);
    }
  }
}

// ---------------- attention v1 (fallback path, per-n, qkv[row][1152]) ----------------
__global__ void attn_kernel(const u16* __restrict__ qkv, const u16* __restrict__ relH,
                            const u16* __restrict__ relW, u16* __restrict__ outp, int n0){
  __shared__ u16 Qt[64 * 72];
  __shared__ u16 Kt[64 * 72];
  __shared__ u16 Vt[48 * 72];
  __shared__ float rH[511], rW[511];
  const int tid = threadIdx.x, lane = tid & 63, w = tid >> 6;
  const int bid = blockIdx.x;
  const int ln_ = bid >> 7;
  const int n = n0 + ln_;
  const int h = (bid >> 4) & 7;
  const int q0 = (bid & 15) << 6;
  const short8 zz = {0, 0, 0, 0, 0, 0, 0, 0};

  for (int i = tid; i < 511; i += 256){ rH[i] = bf2f(relH[i * 8 + h]); rW[i] = bf2f(relW[i * 8 + h]); }
  const size_t baseQ = ((size_t)(ln_ * 1024 + q0)) * 1152 + h * 48;
  for (int c8 = tid; c8 < 512; c8 += 256){
    int ch = c8 >> 6, r = c8 & 63;
    short8 qv = zz;
    if (ch < 6) qv = *(const short8*)&qkv[baseQ + (size_t)r * 1152 + ch * 8];
    *(short8*)&Qt[r * 72 + ch * 8] = qv;
  }
  __syncthreads();
  const int kk = (lane >> 4) << 3;
  short8 aQ0 = *(const short8*)&Qt[(w * 16 + (lane & 15)) * 72 + kk];
  short8 aQ1 = *(const short8*)&Qt[(w * 16 + (lane & 15)) * 72 + 32 + kk];
  u16* Pt = Qt;

  float mrow[4], lrow[4];
  f32x4 oac[3];
  f32x4 zero4 = {0.f, 0.f, 0.f, 0.f};
#pragma unroll
  for (int j = 0; j < 4; ++j){ mrow[j] = -1e30f; lrow[j] = 0.f; }
#pragma unroll
  for (int d3 = 0; d3 < 3; ++d3) oac[d3] = zero4;

  int qh_[4], qw_[4];
#pragma unroll
  for (int j = 0; j < 4; ++j){
    int qi = q0 + w * 16 + ((lane >> 4) << 2) + j;
    qh_[j] = qi >> 5; qw_[j] = qi & 31;
  }

  for (int kt = 0; kt < 16; ++kt){
    int kv0 = kt << 6;
    const size_t baseKV = ((size_t)(ln_ * 1024 + kv0)) * 1152 + h * 48;
    __syncthreads();
    for (int c8 = tid; c8 < 512; c8 += 256){
      int ch = c8 >> 6, r = c8 & 63;
      short8 kv = zz;
      if (ch < 6){
        kv = *(const short8*)&qkv[baseKV + 384 + (size_t)r * 1152 + ch * 8];
        short8 vv = *(const short8*)&qkv[baseKV + 768 + (size_t)r * 1152 + ch * 8];
#pragma unroll
        for (int i = 0; i < 8; ++i) Vt[(ch * 8 + i) * 72 + r] = (u16)vv[i];
      }
      *(short8*)&Kt[r * 72 + ch * 8] = kv;
    }
    __syncthreads();

    f32x4 sc[4];
#pragma unroll
    for (int nn = 0; nn < 4; ++nn) sc[nn] = zero4;
#pragma unroll
    for (int nn = 0; nn < 4; ++nn){
      short8 bK0 = *(const short8*)&Kt[(nn * 16 + (lane & 15)) * 72 + kk];
      sc[nn] = __builtin_amdgcn_mfma_f32_16x16x32_bf16(aQ0, bK0, sc[nn], 0, 0, 0);
      short8 bK1 = *(const short8*)&Kt[(nn * 16 + (lane & 15)) * 72 + 32 + kk];
      sc[nn] = __builtin_amdgcn_mfma_f32_16x16x32_bf16(aQ1, bK1, sc[nn], 0, 0, 0);
    }

#pragma unroll
    for (int j = 0; j < 4; ++j){
      float pv[4];
      float tm = -1e30f;
#pragma unroll
      for (int nn = 0; nn < 4; ++nn){
        int kj = kv0 + nn * 16 + (lane & 15);
        float sv = sc[nn][j] * AT_SCALE + rH[qh_[j] - (kj >> 5) + 255] + rW[qw_[j] - (kj & 31) + 255];
        pv[nn] = sv;
        tm = fmaxf(tm, sv);
      }
      tm = fmaxf(tm, __shfl_xor(tm, 1));
      tm = fmaxf(tm, __shfl_xor(tm, 2));
      tm = fmaxf(tm, __shfl_xor(tm, 4));
      tm = fmaxf(tm, __shfl_xor(tm, 8));
      float mnew = fmaxf(mrow[j], tm);
      float corr = __expf(mrow[j] - mnew);
      mrow[j] = mnew;
      float ps = 0.f;
#pragma unroll
      for (int nn = 0; nn < 4; ++nn){
        float e = __expf(pv[nn] - mnew);
        ps += e;
        Pt[(w * 16 + ((lane >> 4) << 2) + j) * 72 + nn * 16 + (lane & 15)] = f2bf(e);
      }
      ps += __shfl_xor(ps, 1);
      ps += __shfl_xor(ps, 2);
      ps += __shfl_xor(ps, 4);
      ps += __shfl_xor(ps, 8);
      lrow[j] = lrow[j] * corr + ps;
#pragma unroll
      for (int d3 = 0; d3 < 3; ++d3) oac[d3][j] *= corr;
    }

#pragma unroll
    for (int k0i = 0; k0i < 2; ++k0i){
      short8 aP = *(const short8*)&Pt[(w * 16 + (lane & 15)) * 72 + k0i * 32 + kk];
#pragma unroll
      for (int d3 = 0; d3 < 3; ++d3){
        short8 bV = *(const short8*)&Vt[(d3 * 16 + (lane & 15)) * 72 + k0i * 32 + kk];
        oac[d3] = __builtin_amdgcn_mfma_f32_16x16x32_bf16(aP, bV, oac[d3], 0, 0, 0);
      }
    }
  }

#pragma unroll
  for (int d3 = 0; d3 < 3; ++d3)
#pragma unroll
    for (int j = 0; j < 4; ++j){
      int row = q0 + w * 16 + ((lane >> 4) << 2) + j;
      int col = h * 48 + d3 * 16 + (lane & 15);
      float v = oac[d3][j] / lrow[j];
      outp[(size_t)(n * 1024 + row) * 384 + col] = f2bf(v);
    }
}

// ---------------- final: out[n][c][l] = x2[n][l][c] + m2[n][l][c], flag-aware dtype ----------------
__global__ void final_add(const u16* __restrict__ x2, const u16* __restrict__ m2,
                          void* __restrict__ out, const int* __restrict__ flag){
  __shared__ float ts[32][65];
  bool isbf = (*flag != 0);
  int bid = blockIdx.x;
  int n = bid / 192;
  int rem = bid % 192;
  int c0 = (rem / 16) * 32;
  int l0 = (rem % 16) * 64;
  int t = threadIdx.x;
#pragma unroll
  for (int i = 0; i < 8; ++i){
    int lr = (t >> 5) + i * 8, cr = t & 31;
    size_t src = (size_t)(n * 1024 + l0 + lr) * 384 + c0 + cr;
    ts[cr][lr] = bf2f(x2[src]) + bf2f(m2[src]);
  }
  __syncthreads();
#pragma unroll
  for (int i = 0; i < 8; ++i){
    int cw = (t >> 6) + i * 4, lw = t & 63;
    size_t oidx = (size_t)(n * 384 + c0 + cw) * 1024 + l0 + lw;
    if (isbf) ((u16*)out)[oidx] = f2bf(ts[cw][lw]);
    else      ((float*)out)[oidx] = ts[cw][lw];
  }
}

extern "C" void kernel_launch(void* const* d_in, const int* in_sizes, int n_in,
                              void* d_out, int out_size, void* d_ws, size_t ws_size,
                              hipStream_t stream){
  (void)in_sizes; (void)n_in; (void)out_size;
  char* ws = (char*)d_ws;
  size_t off = 0;
  auto alloc = [&](size_t bytes) -> char* {
    char* p = ws + off;
    off += ((bytes + 255) & ~(size_t)255);
    return p;
  };
  // ---- common layout ----
  int* flag   = (int*)alloc(256);
  u16* wTqkv  = (u16*)alloc((size_t)1152 * 384 * 2);
  u16* wTproj = (u16*)alloc((size_t)384 * 384 * 2);
  u16* wTm1   = (u16*)alloc((size_t)1536 * 384 * 2);
  u16* wTm2   = (u16*)alloc((size_t)384 * 1536 * 2);
  u16* bqkvc  = (u16*)alloc(1152 * 2);
  u16* bprojc = (u16*)alloc(384 * 2);
  u16* ln1gc  = (u16*)alloc(384 * 2);
  u16* ln1bc  = (u16*)alloc(384 * 2);
  u16* ln2gc  = (u16*)alloc(384 * 2);
  u16* ln2bc  = (u16*)alloc(384 * 2);
  u16* bm1c   = (u16*)alloc(1536 * 2);
  u16* bm2c   = (u16*)alloc(384 * 2);
  u16* relHc  = (u16*)alloc(4088 * 2);
  u16* relWc  = (u16*)alloc(4088 * 2);
  u16* x2     = (u16*)alloc((size_t)8192 * 384 * 2);
  size_t off_common = off;

  char* BIG1 = alloc((size_t)8192 * 384 * 2);           // 6.29 MB
  char* BIG2 = alloc((size_t)8192 * 1152 * 2);          // 18.87 MB
  bool big = (off <= ws_size);
  char* BIG3 = alloc((size_t)8192 * 1536 * 2 - (size_t)8192 * 1152 * 2);
  char* BIG4 = alloc((size_t)8192 * 384 * 2);
  bool huge = (off <= ws_size);
  (void)BIG3;

  // ---- fused canonicalization (small inputs only; x/pos consumed raw) ----
  {
    ConvArgs a;
    const int srcidx[10] = {3, 5, 6, 7, 8, 9, 11, 13, 14, 15};
    u16* dsts[10] = {bqkvc, bprojc, ln1gc, ln1bc, ln2gc, ln2bc, bm1c, bm2c, relHc, relWc};
    const int n4s[10] = {288, 96, 96, 96, 96, 96, 384, 96, 1022, 1022};
    int c = 0;
    for (int i = 0; i < 10; ++i){
      a.src[i] = d_in[srcidx[i]];
      a.dst[i] = dsts[i];
      a.cum[i] = c;
      c += n4s[i];
    }
    a.cum[10] = c; a.cum[11] = c; a.cum[12] = c;
    a.src[10] = a.src[11] = nullptr; a.dst[10] = a.dst[11] = nullptr;
    convert_all<<<dim3(16), 256, 0, stream>>>(a, (const unsigned*)d_in[0], flag);
  }
  {
    TransArgs t;
    t.src[0] = d_in[2];  t.dst[0] = wTqkv;  t.R[0] = 384;  t.C[0] = 1152;
    t.src[1] = d_in[4];  t.dst[1] = wTproj; t.R[1] = 384;  t.C[1] = 384;
    t.src[2] = d_in[10]; t.dst[2] = wTm1;   t.R[2] = 384;  t.C[2] = 1536;
    t.src[3] = d_in[12]; t.dst[3] = wTm2;   t.R[3] = 1536; t.C[3] = 384;
    t.cumb[0] = 0; t.cumb[1] = 432; t.cumb[2] = 576; t.cumb[3] = 1152; t.cumb[4] = 1728;
    transpose_all<<<dim3(1728), 256, 0, stream>>>(t, (const unsigned*)d_in[0]);
  }

  if (big){
    u16* xf    = (u16*)BIG1;
    u16* attno = (u16*)BIG1;
    u16* y2    = (u16*)BIG1;
    u16* qkbuf = (u16*)BIG2;                               // [8192][768]
    u16* VT    = (u16*)(BIG2 + (size_t)8192 * 768 * 2);    // [8][8][48][1024]

    ln1_pos_kernel<<<dim3(512), 256, 0, stream>>>(d_in[0], d_in[1], ln1gc, ln1bc, xf, 0);
    gemm128<4, 4, 4><<<dim3(576), 256, 0, stream>>>(xf, wTqkv, bqkvc, qkbuf, nullptr, 8192, 384, 1152, 0, flag, VT);
    attn7_kernel<<<dim3(1024), 256, 0, stream>>>(qkbuf, VT, relHc, relWc, attno);
    gemm128<1, 3, 2><<<dim3(512), 256, 0, stream>>>(attno, wTproj, bprojc, x2, d_in[0], 8192, 384, 384, 0, flag, nullptr);
    ln_row<<<dim3(2048), 256, 0, stream>>>(x2, ln2gc, ln2bc, y2);
    if (huge){
      u16* m1 = (u16*)BIG2;
      u16* m2 = (u16*)BIG4;
      gemm128<2, 4, 4><<<dim3(768), 256, 0, stream>>>(y2, wTm1, bm1c, m1, nullptr, 8192, 384, 1536, 0, flag, nullptr);
      gemm128<0, 3, 2><<<dim3(512), 256, 0, stream>>>(m1, wTm2, bm2c, m2, nullptr, 8192, 1536, 384, 0, flag, nullptr);
      final_add<<<dim3(1536), 256, 0, stream>>>(x2, m2, d_out, flag);
    } else {
      u16* m1h = (u16*)BIG2;
      u16* m2  = (u16*)(BIG2 + (size_t)4096 * 1536 * 2);
      for (int hf = 0; hf < 2; ++hf){
        gemm128<2, 4, 4><<<dim3(384), 256, 0, stream>>>(y2 + (size_t)hf * 4096 * 384, wTm1, bm1c, m1h,
                                                        nullptr, 4096, 384, 1536, 0, flag, nullptr);
        gemm128<0, 3, 2><<<dim3(256), 256, 0, stream>>>(m1h, wTm2, bm2c, m2 + (size_t)hf * 4096 * 384,
                                                        nullptr, 4096, 1536, 384, 0, flag, nullptr);
      }
      final_add<<<dim3(1536), 256, 0, stream>>>(x2, m2, d_out, flag);
    }
  } else {
    // fallback: proven chunked path
    off = off_common;
    char* S = alloc((size_t)3932160);
    u16* xf_n  = (u16*)S;
    u16* qkv_n = (u16*)(S + 786432);
    u16* y2c   = (u16*)S;
    u16* m1c   = (u16*)(S + 786432);
    u16* attno = (u16*)d_out;

    for (int n = 0; n < 8; ++n){
      ln1_pos_kernel<<<dim3(64), 256, 0, stream>>>(d_in[0], d_in[1], ln1gc, ln1bc, xf_n, n);
      gemm128<0, 4, 4><<<dim3(72), 256, 0, stream>>>(xf_n, wTqkv, bqkvc, qkv_n, nullptr, 1024, 384, 1152, 0, flag, nullptr);
      attn_kernel<<<dim3(128), 256, 0, stream>>>(qkv_n, relHc, relWc, attno, n);
    }
    gemm128<1, 4, 4><<<dim3(192), 256, 0, stream>>>(attno, wTproj, bprojc, x2, d_in[0], 8192, 384, 384, 0, flag, nullptr);
    for (int c = 0; c < 8; ++c){
      ln_row<<<dim3(256), 256, 0, stream>>>(x2 + (size_t)c * 1024 * 384, ln2gc, ln2bc, y2c);
      gemm128<2, 4, 4><<<dim3(96), 256, 0, stream>>>(y2c, wTm1, bm1c, m1c, nullptr, 1024, 384, 1536, 0, flag, nullptr);
      gemm128<3, 4, 4><<<dim3(24), 256, 0, stream>>>(m1c, wTm2, bm2c, d_out, x2, 1024, 1536, 384, c * 1024, flag, nullptr);
    }
  }
}

// Round 18
// 178.465 us; speedup vs baseline: 1.0137x; 1.0137x over previous
//
#include <hip/hip_runtime.h>
#include <hip/hip_bf16.h>

typedef unsigned short u16;
typedef __attribute__((ext_vector_type(8))) short short8;
typedef __attribute__((ext_vector_type(4))) float f32x4;
typedef __attribute__((ext_vector_type(4))) unsigned short us4;

#define DEV __device__ __forceinline__

DEV float bf2f(u16 u){ unsigned v = ((unsigned)u) << 16; float f; __builtin_memcpy(&f, &v, 4); return f; }
DEV u16 f2bf(float f){ __hip_bfloat16 h = __float2bfloat16(f); u16 u; __builtin_memcpy(&u, &h, 2); return u; }
DEV u16 f2bf_fast(float f){ unsigned u; __builtin_memcpy(&u, &f, 4); return (u16)((u + 0x8000u) >> 16); }

DEV void gload_lds16(const void* g, void* l){
  __builtin_amdgcn_global_load_lds((const __attribute__((address_space(1))) void*)g,
                                   (__attribute__((address_space(3))) void*)l, 16, 0, 0);
}

#define INV_LN2 1.4426950408889634f

DEV bool detect_inline(const unsigned* __restrict__ xw){
  int cnt = 0;
#pragma unroll
  for (int i = 0; i < 64; ++i){
    unsigned e = (xw[i] >> 7) & 0xFFu;
    cnt += (e >= 0x68u && e <= 0x8Fu) ? 1 : 0;
  }
  return cnt >= 32;
}

// ---------------- fused flag-aware convert of small inputs ----------------
struct ConvArgs {
  const void* src[12];
  u16* dst[12];
  int cum[13];
};
__global__ void convert_all(ConvArgs a, const unsigned* __restrict__ xw, int* __restrict__ flag){
  bool isbf = detect_inline(xw);
  if (blockIdx.x == 0 && threadIdx.x == 0) *flag = isbf ? 1 : 0;
  int total = a.cum[12];
  for (int g = blockIdx.x * 256 + threadIdx.x; g < total; g += gridDim.x * 256){
    int s = 0;
    while (g >= a.cum[s + 1]) ++s;
    int i = g - a.cum[s];
    if (isbf){
      ((us4*)a.dst[s])[i] = ((const us4*)a.src[s])[i];
    } else {
      f32x4 v = ((const f32x4*)a.src[s])[i];
      us4 o;
#pragma unroll
      for (int j = 0; j < 4; ++j) o[j] = f2bf(v[j]);
      ((us4*)a.dst[s])[i] = o;
    }
  }
}

// ---------------- fused flag-aware 32x32 tiled transposes (4 weights) ----------------
struct TransArgs {
  const void* src[4];
  u16* dst[4];
  int R[4], C[4];
  int cumb[5];
};
__global__ void transpose_all(TransArgs a, const unsigned* __restrict__ xw){
  __shared__ u16 tl[32][33];
  bool isbf = detect_inline(xw);
  int b = blockIdx.x;
  int s = 0;
  while (b >= a.cumb[s + 1]) ++s;
  int lb = b - a.cumb[s];
  const void* in = a.src[s];
  u16* out = a.dst[s];
  int R = a.R[s], Cc = a.C[s];
  int ntc = Cc >> 5;
  int br = lb / ntc, bc = lb % ntc;
  int t = threadIdx.x;
#pragma unroll
  for (int i = 0; i < 4; ++i){
    int r = (t >> 5) + i * 8, c = t & 31;
    size_t idx = (size_t)(br * 32 + r) * Cc + bc * 32 + c;
    tl[r][c] = isbf ? ((const u16*)in)[idx] : f2bf(((const float*)in)[idx]);
  }
  __syncthreads();
#pragma unroll
  for (int i = 0; i < 4; ++i){
    int c = (t >> 5) + i * 8, r = t & 31;
    out[(size_t)(bc * 32 + c) * R + br * 32 + r] = tl[r][c];
  }
}

// ---------------- LN1 v2: vectorized raw reads, 16-l tiles ----------------
__global__ void ln1_pos_kernel(const void* __restrict__ xr, const void* __restrict__ posr,
                               const u16* __restrict__ g, const u16* __restrict__ b,
                               u16* __restrict__ xf, int n0){
  __shared__ u16 xs[384 * 20];
  __shared__ float ps_[64][16], pq_[64][16];
  __shared__ float mls[16], rls[16];
  bool isbf = detect_inline((const unsigned*)xr);
  const int tid = threadIdx.x;
  const int ln_ = blockIdx.x >> 6;
  const int n = n0 + ln_;
  const int l0 = (blockIdx.x & 63) << 4;
  const int cs = tid >> 2;
  const int lq = (tid & 3) << 2;
  float s[4] = {0.f, 0.f, 0.f, 0.f}, sq[4] = {0.f, 0.f, 0.f, 0.f};
#pragma unroll
  for (int it = 0; it < 6; ++it){
    int c = cs + it * 64;
    size_t base = (size_t)(n * 384 + c) * 1024 + l0 + lq;
    float v[4];
    if (isbf){
      us4 u = *(const us4*)((const u16*)xr + base);
#pragma unroll
      for (int i = 0; i < 4; ++i) v[i] = bf2f(u[i]);
    } else {
      f32x4 f = *(const f32x4*)((const float*)xr + base);
#pragma unroll
      for (int i = 0; i < 4; ++i) v[i] = f[i];
    }
    us4 o;
#pragma unroll
    for (int i = 0; i < 4; ++i){
      s[i] += v[i]; sq[i] += v[i] * v[i];
      o[i] = f2bf_fast(v[i]);
    }
    *(us4*)&xs[c * 20 + lq] = o;
  }
#pragma unroll
  for (int i = 0; i < 4; ++i){ ps_[cs][lq + i] = s[i]; pq_[cs][lq + i] = sq[i]; }
  __syncthreads();
  for (int st = 32; st >= 1; st >>= 1){
    if (cs < st){
#pragma unroll
      for (int i = 0; i < 4; ++i){
        ps_[cs][lq + i] += ps_[cs + st][lq + i];
        pq_[cs][lq + i] += pq_[cs + st][lq + i];
      }
    }
    __syncthreads();
  }
  if (tid < 16){
    float mean = ps_[0][tid] * (1.f / 384.f);
    float var = pq_[0][tid] * (1.f / 384.f) - mean * mean;
    mls[tid] = mean; rls[tid] = rsqrtf(fmaxf(var, 0.f) + 1e-5f);
  }
  __syncthreads();
  for (int idx = tid; idx < 384 * 16; idx += 256){
    int c = idx % 384, l = idx / 384;
    size_t pidx = (size_t)(l0 + l) * 384 + c;
    float pv = isbf ? bf2f(((const u16*)posr)[pidx]) : ((const float*)posr)[pidx];
    float v = (bf2f(xs[c * 20 + l]) - mls[l]) * rls[l] * bf2f(g[c]) + bf2f(b[c]) + pv;
    xf[(size_t)(ln_ * 1024 + l0 + l) * 384 + c] = f2bf_fast(v);
  }
}

// ---------------- rowwise LN over last dim of [rows][384] ----------------
__global__ void ln_row(const u16* __restrict__ in, const u16* __restrict__ g,
                       const u16* __restrict__ b, u16* __restrict__ out){
  int w = threadIdx.x >> 6, lane = threadIdx.x & 63;
  size_t row = (size_t)blockIdx.x * 4 + w;
  const u16* r = in + row * 384;
  float v[6]; float s = 0.f, sq = 0.f;
#pragma unroll
  for (int i = 0; i < 6; ++i){ v[i] = bf2f(r[lane + i * 64]); s += v[i]; sq += v[i] * v[i]; }
#pragma unroll
  for (int m = 1; m < 64; m <<= 1){ s += __shfl_xor(s, m); sq += __shfl_xor(sq, m); }
  float mean = s * (1.f / 384.f);
  float var = sq * (1.f / 384.f) - mean * mean;
  float rv = rsqrtf(fmaxf(var, 0.f) + 1e-5f);
#pragma unroll
  for (int i = 0; i < 6; ++i){
    int c = lane + i * 64;
    out[row * 384 + c] = f2bf_fast((v[i] - mean) * rv * bf2f(g[c]) + bf2f(b[c]));
  }
}

// ====== (MF*32)x(NF*32) MFMA GEMM, 2-phase double-buffered LDS, K-step=KB ======
// MODE 0: +bias   MODE 1: +bias+resid[NCHW gather, flag-aware raw]   MODE 2: +bias tanh-GELU
// MODE 3: +bias+resid2[NLC]; NCL flag-aware write (fallback)   MODE 4: qkv split-write
template<int MODE, int NF, int MF, int KB = 32>
__global__ void gemm128(const u16* __restrict__ A, const u16* __restrict__ BT,
                        const u16* __restrict__ bias, void* __restrict__ Co,
                        const void* __restrict__ resid, int M, int K, int Nn, int row0,
                        const int* __restrict__ oflag, u16* __restrict__ vt){
  (void)M;
  __shared__ u16 lsA[2][MF * 32 * KB];
  __shared__ u16 lsB[2][NF * 32 * KB];
  const int BM = MF * 32, BN = NF * 32;
  const int ntN = Nn / BN;
  int bid = blockIdx.x;
  {
    int nwg = gridDim.x;
    if ((nwg & 7) == 0){ int per = nwg >> 3; bid = (bid & 7) * per + (bid >> 3); }
  }
  const int bm = bid / ntN;
  const int bn = bid % ntN;
  const int tid = threadIdx.x;
  const int lane = tid & 63;
  const int w = tid >> 6;
  const int wr = w >> 1, wc = w & 1;
  const u16* Ab = A + (size_t)bm * BM * K;
  const u16* Bb = BT + (size_t)bn * BN * K;
  bool robf = false;
  if (MODE == 1 || MODE == 3) robf = (*oflag != 0);

  constexpr int CPR  = KB / 8;              // 16B chunks per row
  constexpr int NCHA = MF * 32 * CPR;       // chunks per A buffer
  constexpr int NCHB = NF * 32 * CPR;
  auto stage = [&](int buf, int k0){
#pragma unroll
    for (int i = 0; i < (NCHA + 255) / 256; ++i){
      int c = i * 256 + tid;
      if ((NCHA % 256 == 0) || c < NCHA){
        int row = c / CPR, cc = c % CPR;
        gload_lds16(Ab + (size_t)row * K + k0 + cc * 8,
                    (char*)(&lsA[buf][0]) + (size_t)(i * 256 + w * 64) * 16);
      }
    }
#pragma unroll
    for (int i = 0; i < (NCHB + 255) / 256; ++i){
      int c = i * 256 + tid;
      if ((NCHB % 256 == 0) || c < NCHB){
        int row = c / CPR, cc = c % CPR;
        gload_lds16(Bb + (size_t)row * K + k0 + cc * 8,
                    (char*)(&lsB[buf][0]) + (size_t)(i * 256 + w * 64) * 16);
      }
    }
  };

  f32x4 zero4 = {0.f, 0.f, 0.f, 0.f};
  f32x4 acc[MF][NF];
#pragma unroll
  for (int m = 0; m < MF; ++m)
#pragma unroll
    for (int nn = 0; nn < NF; ++nn) acc[m][nn] = zero4;
  const int kk = (lane >> 4) << 3;

  stage(0, 0);
  __syncthreads();
  int cur = 0;
  for (int k0 = 0; k0 < K; k0 += KB){
    if (k0 + KB < K) stage(cur ^ 1, k0 + KB);
#pragma unroll
    for (int ks = 0; ks < KB / 32; ++ks){
      short8 af[MF], bfr[NF];
#pragma unroll
      for (int m = 0; m < MF; ++m)
        af[m] = *(const short8*)&lsA[cur][(wr * MF * 16 + m * 16 + (lane & 15)) * KB + ks * 32 + kk];
#pragma unroll
      for (int nn = 0; nn < NF; ++nn)
        bfr[nn] = *(const short8*)&lsB[cur][(wc * NF * 16 + nn * 16 + (lane & 15)) * KB + ks * 32 + kk];
      __builtin_amdgcn_s_setprio(1);
#pragma unroll
      for (int m = 0; m < MF; ++m)
#pragma unroll
        for (int nn = 0; nn < NF; ++nn)
          acc[m][nn] = __builtin_amdgcn_mfma_f32_16x16x32_bf16(af[m], bfr[nn], acc[m][nn], 0, 0, 0);
      __builtin_amdgcn_s_setprio(0);
    }
    __syncthreads();
    cur ^= 1;
  }

#pragma unroll
  for (int m = 0; m < MF; ++m){
#pragma unroll
    for (int nn = 0; nn < NF; ++nn){
#pragma unroll
      for (int j = 0; j < 4; ++j){
        int row = bm * BM + wr * MF * 16 + m * 16 + ((lane >> 4) << 2) + j;
        int col = bn * BN + wc * NF * 16 + nn * 16 + (lane & 15);
        float v = acc[m][nn][j] + bf2f(bias[col]);
        if (MODE == 2){
          float y = 0.7978845608028654f * fmaf(0.044715f * v * v, v, v);
          v = v / (1.f + exp2f(-2.8853900817779268f * y));
        }
        if (MODE == 1){
          int rg = row0 + row;
          size_t ridx = ((size_t)((rg >> 10) * 384 + col)) * 1024 + (rg & 1023);
          v += robf ? bf2f(((const u16*)resid)[ridx]) : ((const float*)resid)[ridx];
          ((u16*)Co)[(size_t)row * Nn + col] = f2bf_fast(v);
        } else if (MODE == 3){
          int rg = row0 + row;
          v += bf2f(((const u16*)resid)[(size_t)rg * 384 + col]);
          size_t oidx = ((size_t)((rg >> 10) * 384 + col)) * 1024 + (rg & 1023);
          if (robf) ((u16*)Co)[oidx] = f2bf(v);
          else      ((float*)Co)[oidx] = v;
        } else if (MODE == 4){
          if (col < 768){
            ((u16*)Co)[(size_t)row * 768 + col] = f2bf_fast(v);
          } else {
            int vc = col - 768;
            int vh = vc / 48, vd = vc % 48;
            vt[((size_t)(((row >> 10) * 8 + vh) * 48 + vd)) * 1024 + (row & 1023)] = f2bf_fast(v);
          }
        } else {
          ((u16*)Co)[(size_t)row * Nn + col] = f2bf_fast(v);
        }
      }
    }
  }
}

#define AT_SCALE 0.14433756729740643f
#define AT_SCALE2 (0.14433756729740643f * 1.4426950408889634f)

// ---------------- attention v5 (proven best): no-max softmax, 256 thr, grid 1024 ----------------
__global__ __launch_bounds__(256, 4)
void attn5_kernel(const u16* __restrict__ qk, const u16* __restrict__ vtg,
                  const u16* __restrict__ relH, const u16* __restrict__ relW,
                  u16* __restrict__ outp){
  __shared__ u16 Pt[64 * 72];
  __shared__ u16 Kt[64 * 72];
  __shared__ u16 Vt[48 * 72];
  __shared__ float rH[511], rW[511];
  const int tid = threadIdx.x, lane = tid & 63, w = tid >> 6;
  const int d = blockIdx.x;
  const int g = ((d >> 7) << 3) | (d & 7);
  const int m_ = (d >> 3) & 15;
  const int n = g >> 3;
  const int h = g & 7;
  const int q0 = m_ << 6;
  const short8 zz = {0, 0, 0, 0, 0, 0, 0, 0};

  for (int i = tid; i < 511; i += 256){
    rH[i] = bf2f(relH[i * 8 + h]) * INV_LN2;
    rW[i] = bf2f(relW[i * 8 + h]) * INV_LN2;
  }
  const size_t baseVT = ((size_t)((n * 8 + h) * 48)) * 1024;
  const int kk = (lane >> 4) << 3;

  const size_t baseQr = ((size_t)(n * 1024 + q0 + w * 16 + (lane & 15))) * 768 + h * 48;
  short8 aQ0 = *(const short8*)&qk[baseQr + kk];
  short8 aQ1 = (kk < 16) ? *(const short8*)&qk[baseQr + 32 + kk] : zz;

  short8 kr0, kr1, vr0, vr1;
  const int k0r = tid >> 3, k0c = tid & 7;
  const int k1r = (tid + 256) >> 3;
  const int v0d = tid >> 3, v0l = tid & 7;
  const int v1d = (tid + 256) >> 3;
  auto loadKV = [&](int kt1){
    int kv0 = kt1 << 6;
    size_t bK = ((size_t)(n * 1024 + kv0)) * 768 + 384 + h * 48;
    kr0 = (k0c < 6) ? *(const short8*)&qk[bK + (size_t)k0r * 768 + k0c * 8] : zz;
    kr1 = (k0c < 6) ? *(const short8*)&qk[bK + (size_t)k1r * 768 + k0c * 8] : zz;
    vr0 = *(const short8*)&vtg[baseVT + (size_t)v0d * 1024 + kv0 + v0l * 8];
    if (tid < 128) vr1 = *(const short8*)&vtg[baseVT + (size_t)v1d * 1024 + kv0 + v0l * 8];
  };
  auto writeKV = [&](){
    *(short8*)&Kt[k0r * 72 + k0c * 8] = kr0;
    *(short8*)&Kt[k1r * 72 + k0c * 8] = kr1;
    *(short8*)&Vt[v0d * 72 + v0l * 8] = vr0;
    if (tid < 128) *(short8*)&Vt[v1d * 72 + v0l * 8] = vr1;
  };

  loadKV(0);
  writeKV();
  __syncthreads();

  float lsum[4];
  f32x4 oac[3];
  f32x4 zero4 = {0.f, 0.f, 0.f, 0.f};
#pragma unroll
  for (int j = 0; j < 4; ++j) lsum[j] = 0.f;
#pragma unroll
  for (int d3 = 0; d3 < 3; ++d3) oac[d3] = zero4;

  int qh_[4];
  float rw0_[4], rw1_[4];
#pragma unroll
  for (int j = 0; j < 4; ++j){
    int qi = q0 + w * 16 + ((lane >> 4) << 2) + j;
    qh_[j] = qi >> 5;
    int qw = qi & 31;
    rw0_[j] = rW[qw - (lane & 15) + 255];
    rw1_[j] = rW[qw - (lane & 15) + 239];
  }

  for (int kt = 0; kt < 16; ++kt){
    f32x4 sc[4];
#pragma unroll
    for (int nn = 0; nn < 4; ++nn) sc[nn] = zero4;
    __builtin_amdgcn_s_setprio(1);
#pragma unroll
    for (int nn = 0; nn < 4; ++nn){
      short8 bK0 = *(const short8*)&Kt[(nn * 16 + (lane & 15)) * 72 + kk];
      sc[nn] = __builtin_amdgcn_mfma_f32_16x16x32_bf16(aQ0, bK0, sc[nn], 0, 0, 0);
      short8 bK1 = *(const short8*)&Kt[(nn * 16 + (lane & 15)) * 72 + 32 + kk];
      sc[nn] = __builtin_amdgcn_mfma_f32_16x16x32_bf16(aQ1, bK1, sc[nn], 0, 0, 0);
    }
    __builtin_amdgcn_s_setprio(0);

    if (kt < 15) loadKV(kt + 1);

#pragma unroll
    for (int j = 0; j < 4; ++j){
      int ih = qh_[j] - (kt << 1) + 255;
      float rh0 = rH[ih], rh1 = rH[ih - 1];
      float e0 = exp2f(fmaf(sc[0][j], AT_SCALE2, rh0 + rw0_[j]));
      float e1 = exp2f(fmaf(sc[1][j], AT_SCALE2, rh0 + rw1_[j]));
      float e2 = exp2f(fmaf(sc[2][j], AT_SCALE2, rh1 + rw0_[j]));
      float e3 = exp2f(fmaf(sc[3][j], AT_SCALE2, rh1 + rw1_[j]));
      lsum[j] += (e0 + e1) + (e2 + e3);
      int prow = (w * 16 + ((lane >> 4) << 2) + j) * 72 + (lane & 15);
      Pt[prow]      = f2bf_fast(e0);
      Pt[prow + 16] = f2bf_fast(e1);
      Pt[prow + 32] = f2bf_fast(e2);
      Pt[prow + 48] = f2bf_fast(e3);
    }

    __builtin_amdgcn_s_setprio(1);
#pragma unroll
    for (int k0i = 0; k0i < 2; ++k0i){
      short8 aP = *(const short8*)&Pt[(w * 16 + (lane & 15)) * 72 + k0i * 32 + kk];
#pragma unroll
      for (int d3 = 0; d3 < 3; ++d3){
        short8 bV = *(const short8*)&Vt[(d3 * 16 + (lane & 15)) * 72 + k0i * 32 + kk];
        oac[d3] = __builtin_amdgcn_mfma_f32_16x16x32_bf16(aP, bV, oac[d3], 0, 0, 0);
      }
    }
    __builtin_amdgcn_s_setprio(0);

    if (kt < 15){
      __syncthreads();
      writeKV();
      __syncthreads();
    }
  }

#pragma unroll
  for (int j = 0; j < 4; ++j){
    float l = lsum[j];
    l += __shfl_xor(l, 1);
    l += __shfl_xor(l, 2);
    l += __shfl_xor(l, 4);
    l += __shfl_xor(l, 8);
    float rl = 1.0f / l;
    int row = q0 + w * 16 + ((lane >> 4) << 2) + j;
#pragma unroll
    for (int d3 = 0; d3 < 3; ++d3){
      int col = h * 48 + d3 * 16 + (lane & 15);
      outp[(size_t)(n * 1024 + row) * 384 + col] = f2bf_fast(oac[d3][j] * rl);
    }
  }
}

// ---------------- attention v1 (fallback path, per-n, qkv[row][1152]) ----------------
__global__ void attn_kernel(const u16* __restrict__ qkv, const u16* __restrict__ relH,
                            const u16* __restrict__ relW, u16* __restrict__ outp, int n0){
  __shared__ u16 Qt[64 * 72];
  __shared__ u16 Kt[64 * 72];
  __shared__ u16 Vt[48 * 72];
  __shared__ float rH[511], rW[511];
  const int tid = threadIdx.x, lane = tid & 63, w = tid >> 6;
  const int bid = blockIdx.x;
  const int ln_ = bid >> 7;
  const int n = n0 + ln_;
  const int h = (bid >> 4) & 7;
  const int q0 = (bid & 15) << 6;
  const short8 zz = {0, 0, 0, 0, 0, 0, 0, 0};

  for (int i = tid; i < 511; i += 256){ rH[i] = bf2f(relH[i * 8 + h]); rW[i] = bf2f(relW[i * 8 + h]); }
  const size_t baseQ = ((size_t)(ln_ * 1024 + q0)) * 1152 + h * 48;
  for (int c8 = tid; c8 < 512; c8 += 256){
    int ch = c8 >> 6, r = c8 & 63;
    short8 qv = zz;
    if (ch < 6) qv = *(const short8*)&qkv[baseQ + (size_t)r * 1152 + ch * 8];
    *(short8*)&Qt[r * 72 + ch * 8] = qv;
  }
  __syncthreads();
  const int kk = (lane >> 4) << 3;
  short8 aQ0 = *(const short8*)&Qt[(w * 16 + (lane & 15)) * 72 + kk];
  short8 aQ1 = *(const short8*)&Qt[(w * 16 + (lane & 15)) * 72 + 32 + kk];
  u16* Pt = Qt;

  float mrow[4], lrow[4];
  f32x4 oac[3];
  f32x4 zero4 = {0.f, 0.f, 0.f, 0.f};
#pragma unroll
  for (int j = 0; j < 4; ++j){ mrow[j] = -1e30f; lrow[j] = 0.f; }
#pragma unroll
  for (int d3 = 0; d3 < 3; ++d3) oac[d3] = zero4;

  int qh_[4], qw_[4];
#pragma unroll
  for (int j = 0; j < 4; ++j){
    int qi = q0 + w * 16 + ((lane >> 4) << 2) + j;
    qh_[j] = qi >> 5; qw_[j] = qi & 31;
  }

  for (int kt = 0; kt < 16; ++kt){
    int kv0 = kt << 6;
    const size_t baseKV = ((size_t)(ln_ * 1024 + kv0)) * 1152 + h * 48;
    __syncthreads();
    for (int c8 = tid; c8 < 512; c8 += 256){
      int ch = c8 >> 6, r = c8 & 63;
      short8 kv = zz;
      if (ch < 6){
        kv = *(const short8*)&qkv[baseKV + 384 + (size_t)r * 1152 + ch * 8];
        short8 vv = *(const short8*)&qkv[baseKV + 768 + (size_t)r * 1152 + ch * 8];
#pragma unroll
        for (int i = 0; i < 8; ++i) Vt[(ch * 8 + i) * 72 + r] = (u16)vv[i];
      }
      *(short8*)&Kt[r * 72 + ch * 8] = kv;
    }
    __syncthreads();

    f32x4 sc[4];
#pragma unroll
    for (int nn = 0; nn < 4; ++nn) sc[nn] = zero4;
#pragma unroll
    for (int nn = 0; nn < 4; ++nn){
      short8 bK0 = *(const short8*)&Kt[(nn * 16 + (lane & 15)) * 72 + kk];
      sc[nn] = __builtin_amdgcn_mfma_f32_16x16x32_bf16(aQ0, bK0, sc[nn], 0, 0, 0);
      short8 bK1 = *(const short8*)&Kt[(nn * 16 + (lane & 15)) * 72 + 32 + kk];
      sc[nn] = __builtin_amdgcn_mfma_f32_16x16x32_bf16(aQ1, bK1, sc[nn], 0, 0, 0);
    }

#pragma unroll
    for (int j = 0; j < 4; ++j){
      float pv[4];
      float tm = -1e30f;
#pragma unroll
      for (int nn = 0; nn < 4; ++nn){
        int kj = kv0 + nn * 16 + (lane & 15);
        float sv = sc[nn][j] * AT_SCALE + rH[qh_[j] - (kj >> 5) + 255] + rW[qw_[j] - (kj & 31) + 255];
        pv[nn] = sv;
        tm = fmaxf(tm, sv);
      }
      tm = fmaxf(tm, __shfl_xor(tm, 1));
      tm = fmaxf(tm, __shfl_xor(tm, 2));
      tm = fmaxf(tm, __shfl_xor(tm, 4));
      tm = fmaxf(tm, __shfl_xor(tm, 8));
      float mnew = fmaxf(mrow[j], tm);
      float corr = __expf(mrow[j] - mnew);
      mrow[j] = mnew;
      float ps = 0.f;
#pragma unroll
      for (int nn = 0; nn < 4; ++nn){
        float e = __expf(pv[nn] - mnew);
        ps += e;
        Pt[(w * 16 + ((lane >> 4) << 2) + j) * 72 + nn * 16 + (lane & 15)] = f2bf(e);
      }
      ps += __shfl_xor(ps, 1);
      ps += __shfl_xor(ps, 2);
      ps += __shfl_xor(ps, 4);
      ps += __shfl_xor(ps, 8);
      lrow[j] = lrow[j] * corr + ps;
#pragma unroll
      for (int d3 = 0; d3 < 3; ++d3) oac[d3][j] *= corr;
    }

#pragma unroll
    for (int k0i = 0; k0i < 2; ++k0i){
      short8 aP = *(const short8*)&Pt[(w * 16 + (lane & 15)) * 72 + k0i * 32 + kk];
#pragma unroll
      for (int d3 = 0; d3 < 3; ++d3){
        short8 bV = *(const short8*)&Vt[(d3 * 16 + (lane & 15)) * 72 + k0i * 32 + kk];
        oac[d3] = __builtin_amdgcn_mfma_f32_16x16x32_bf16(aP, bV, oac[d3], 0, 0, 0);
      }
    }
  }

#pragma unroll
  for (int d3 = 0; d3 < 3; ++d3)
#pragma unroll
    for (int j = 0; j < 4; ++j){
      int row = q0 + w * 16 + ((lane >> 4) << 2) + j;
      int col = h * 48 + d3 * 16 + (lane & 15);
      float v = oac[d3][j] / lrow[j];
      outp[(size_t)(n * 1024 + row) * 384 + col] = f2bf(v);
    }
}

// ---------------- final: out[n][c][l] = x2[n][l][c] + m2[n][l][c], flag-aware dtype ----------------
__global__ void final_add(const u16* __restrict__ x2, const u16* __restrict__ m2,
                          void* __restrict__ out, const int* __restrict__ flag){
  __shared__ float ts[32][65];
  bool isbf = (*flag != 0);
  int bid = blockIdx.x;
  int n = bid / 192;
  int rem = bid % 192;
  int c0 = (rem / 16) * 32;
  int l0 = (rem % 16) * 64;
  int t = threadIdx.x;
#pragma unroll
  for (int i = 0; i < 8; ++i){
    int lr = (t >> 5) + i * 8, cr = t & 31;
    size_t src = (size_t)(n * 1024 + l0 + lr) * 384 + c0 + cr;
    ts[cr][lr] = bf2f(x2[src]) + bf2f(m2[src]);
  }
  __syncthreads();
#pragma unroll
  for (int i = 0; i < 8; ++i){
    int cw = (t >> 6) + i * 4, lw = t & 63;
    size_t oidx = (size_t)(n * 384 + c0 + cw) * 1024 + l0 + lw;
    if (isbf) ((u16*)out)[oidx] = f2bf(ts[cw][lw]);
    else      ((float*)out)[oidx] = ts[cw][lw];
  }
}

extern "C" void kernel_launch(void* const* d_in, const int* in_sizes, int n_in,
                              void* d_out, int out_size, void* d_ws, size_t ws_size,
                              hipStream_t stream){
  (void)in_sizes; (void)n_in; (void)out_size;
  char* ws = (char*)d_ws;
  size_t off = 0;
  auto alloc = [&](size_t bytes) -> char* {
    char* p = ws + off;
    off += ((bytes + 255) & ~(size_t)255);
    return p;
  };
  // ---- common layout ----
  int* flag   = (int*)alloc(256);
  u16* wTqkv  = (u16*)alloc((size_t)1152 * 384 * 2);
  u16* wTproj = (u16*)alloc((size_t)384 * 384 * 2);
  u16* wTm1   = (u16*)alloc((size_t)1536 * 384 * 2);
  u16* wTm2   = (u16*)alloc((size_t)384 * 1536 * 2);
  u16* bqkvc  = (u16*)alloc(1152 * 2);
  u16* bprojc = (u16*)alloc(384 * 2);
  u16* ln1gc  = (u16*)alloc(384 * 2);
  u16* ln1bc  = (u16*)alloc(384 * 2);
  u16* ln2gc  = (u16*)alloc(384 * 2);
  u16* ln2bc  = (u16*)alloc(384 * 2);
  u16* bm1c   = (u16*)alloc(1536 * 2);
  u16* bm2c   = (u16*)alloc(384 * 2);
  u16* relHc  = (u16*)alloc(4088 * 2);
  u16* relWc  = (u16*)alloc(4088 * 2);
  u16* x2     = (u16*)alloc((size_t)8192 * 384 * 2);
  size_t off_common = off;

  char* BIG1 = alloc((size_t)8192 * 384 * 2);           // 6.29 MB
  char* BIG2 = alloc((size_t)8192 * 1152 * 2);          // 18.87 MB
  bool big = (off <= ws_size);
  char* BIG3 = alloc((size_t)8192 * 1536 * 2 - (size_t)8192 * 1152 * 2);
  char* BIG4 = alloc((size_t)8192 * 384 * 2);
  bool huge = (off <= ws_size);
  (void)BIG3;

  // ---- fused canonicalization (small inputs only; x/pos consumed raw) ----
  {
    ConvArgs a;
    const int srcidx[10] = {3, 5, 6, 7, 8, 9, 11, 13, 14, 15};
    u16* dsts[10] = {bqkvc, bprojc, ln1gc, ln1bc, ln2gc, ln2bc, bm1c, bm2c, relHc, relWc};
    const int n4s[10] = {288, 96, 96, 96, 96, 96, 384, 96, 1022, 1022};
    int c = 0;
    for (int i = 0; i < 10; ++i){
      a.src[i] = d_in[srcidx[i]];
      a.dst[i] = dsts[i];
      a.cum[i] = c;
      c += n4s[i];
    }
    a.cum[10] = c; a.cum[11] = c; a.cum[12] = c;
    a.src[10] = a.src[11] = nullptr; a.dst[10] = a.dst[11] = nullptr;
    convert_all<<<dim3(16), 256, 0, stream>>>(a, (const unsigned*)d_in[0], flag);
  }
  {
    TransArgs t;
    t.src[0] = d_in[2];  t.dst[0] = wTqkv;  t.R[0] = 384;  t.C[0] = 1152;
    t.src[1] = d_in[4];  t.dst[1] = wTproj; t.R[1] = 384;  t.C[1] = 384;
    t.src[2] = d_in[10]; t.dst[2] = wTm1;   t.R[2] = 384;  t.C[2] = 1536;
    t.src[3] = d_in[12]; t.dst[3] = wTm2;   t.R[3] = 1536; t.C[3] = 384;
    t.cumb[0] = 0; t.cumb[1] = 432; t.cumb[2] = 576; t.cumb[3] = 1152; t.cumb[4] = 1728;
    transpose_all<<<dim3(1728), 256, 0, stream>>>(t, (const unsigned*)d_in[0]);
  }

  if (big){
    u16* xf    = (u16*)BIG1;
    u16* attno = (u16*)BIG1;
    u16* y2    = (u16*)BIG1;
    u16* qkbuf = (u16*)BIG2;                               // [8192][768]
    u16* VT    = (u16*)(BIG2 + (size_t)8192 * 768 * 2);    // [8][8][48][1024]

    ln1_pos_kernel<<<dim3(512), 256, 0, stream>>>(d_in[0], d_in[1], ln1gc, ln1bc, xf, 0);
    gemm128<4, 4, 4><<<dim3(576), 256, 0, stream>>>(xf, wTqkv, bqkvc, qkbuf, nullptr, 8192, 384, 1152, 0, flag, VT);
    attn5_kernel<<<dim3(1024), 256, 0, stream>>>(qkbuf, VT, relHc, relWc, attno);
    gemm128<1, 3, 2><<<dim3(512), 256, 0, stream>>>(attno, wTproj, bprojc, x2, d_in[0], 8192, 384, 384, 0, flag, nullptr);
    ln_row<<<dim3(2048), 256, 0, stream>>>(x2, ln2gc, ln2bc, y2);
    if (huge){
      u16* m1 = (u16*)BIG2;
      u16* m2 = (u16*)BIG4;
      gemm128<2, 4, 4, 64><<<dim3(768), 256, 0, stream>>>(y2, wTm1, bm1c, m1, nullptr, 8192, 384, 1536, 0, flag, nullptr);
      gemm128<0, 3, 2><<<dim3(512), 256, 0, stream>>>(m1, wTm2, bm2c, m2, nullptr, 8192, 1536, 384, 0, flag, nullptr);
      final_add<<<dim3(1536), 256, 0, stream>>>(x2, m2, d_out, flag);
    } else {
      u16* m1h = (u16*)BIG2;
      u16* m2  = (u16*)(BIG2 + (size_t)4096 * 1536 * 2);
      for (int hf = 0; hf < 2; ++hf){
        gemm128<2, 4, 4, 64><<<dim3(384), 256, 0, stream>>>(y2 + (size_t)hf * 4096 * 384, wTm1, bm1c, m1h,
                                                            nullptr, 4096, 384, 1536, 0, flag, nullptr);
        gemm128<0, 3, 2><<<dim3(256), 256, 0, stream>>>(m1h, wTm2, bm2c, m2 + (size_t)hf * 4096 * 384,
                                                        nullptr, 4096, 1536, 384, 0, flag, nullptr);
      }
      final_add<<<dim3(1536), 256, 0, stream>>>(x2, m2, d_out, flag);
    }
  } else {
    // fallback: proven chunked path
    off = off_common;
    char* S = alloc((size_t)3932160);
    u16* xf_n  = (u16*)S;
    u16* qkv_n = (u16*)(S + 786432);
    u16* y2c   = (u16*)S;
    u16* m1c   = (u16*)(S + 786432);
    u16* attno = (u16*)d_out;

    for (int n = 0; n < 8; ++n){
      ln1_pos_kernel<<<dim3(64), 256, 0, stream>>>(d_in[0], d_in[1], ln1gc, ln1bc, xf_n, n);
      gemm128<0, 4, 4><<<dim3(72), 256, 0, stream>>>(xf_n, wTqkv, bqkvc, qkv_n, nullptr, 1024, 384, 1152, 0, flag, nullptr);
      attn_kernel<<<dim3(128), 256, 0, stream>>>(qkv_n, relHc, relWc, attno, n);
    }
    gemm128<1, 4, 4><<<dim3(192), 256, 0, stream>>>(attno, wTproj, bprojc, x2, d_in[0], 8192, 384, 384, 0, flag, nullptr);
    for (int c = 0; c < 8; ++c){
      ln_row<<<dim3(256), 256, 0, stream>>>(x2 + (size_t)c * 1024 * 384, ln2gc, ln2bc, y2c);
      gemm128<2, 4, 4><<<dim3(96), 256, 0, stream>>>(y2c, wTm1, bm1c, m1c, nullptr, 1024, 384, 1536, 0, flag, nullptr);
      gemm128<3, 4, 4><<<dim3(24), 256, 0, stream>>>(m1c, wTm2, bm2c, d_out, x2, 1024, 1536, 384, c * 1024, flag, nullptr);
    }
  }
}

// Round 19
// 174.779 us; speedup vs baseline: 1.0351x; 1.0211x over previous
//
#include <hip/hip_runtime.h>
#include <hip/hip_bf16.h>

typedef unsigned short u16;
typedef __attribute__((ext_vector_type(8))) short short8;
typedef __attribute__((ext_vector_type(4))) float f32x4;
typedef __attribute__((ext_vector_type(4))) unsigned short us4;

#define DEV __device__ __forceinline__

DEV float bf2f(u16 u){ unsigned v = ((unsigned)u) << 16; float f; __builtin_memcpy(&f, &v, 4); return f; }
DEV u16 f2bf(float f){ __hip_bfloat16 h = __float2bfloat16(f); u16 u; __builtin_memcpy(&u, &h, 2); return u; }
DEV u16 f2bf_fast(float f){ unsigned u; __builtin_memcpy(&u, &f, 4); return (u16)((u + 0x8000u) >> 16); }

DEV void gload_lds16(const void* g, void* l){
  __builtin_amdgcn_global_load_lds((const __attribute__((address_space(1))) void*)g,
                                   (__attribute__((address_space(3))) void*)l, 16, 0, 0);
}

#define INV_LN2 1.4426950408889634f

DEV bool detect_inline(const unsigned* __restrict__ xw){
  int cnt = 0;
#pragma unroll
  for (int i = 0; i < 64; ++i){
    unsigned e = (xw[i] >> 7) & 0xFFu;
    cnt += (e >= 0x68u && e <= 0x8Fu) ? 1 : 0;
  }
  return cnt >= 32;
}

// ---------------- fused flag-aware convert of small inputs ----------------
struct ConvArgs {
  const void* src[12];
  u16* dst[12];
  int cum[13];
};
__global__ void convert_all(ConvArgs a, const unsigned* __restrict__ xw, int* __restrict__ flag){
  bool isbf = detect_inline(xw);
  if (blockIdx.x == 0 && threadIdx.x == 0) *flag = isbf ? 1 : 0;
  int total = a.cum[12];
  for (int g = blockIdx.x * 256 + threadIdx.x; g < total; g += gridDim.x * 256){
    int s = 0;
    while (g >= a.cum[s + 1]) ++s;
    int i = g - a.cum[s];
    if (isbf){
      ((us4*)a.dst[s])[i] = ((const us4*)a.src[s])[i];
    } else {
      f32x4 v = ((const f32x4*)a.src[s])[i];
      us4 o;
#pragma unroll
      for (int j = 0; j < 4; ++j) o[j] = f2bf(v[j]);
      ((us4*)a.dst[s])[i] = o;
    }
  }
}

// ---------------- fused flag-aware 32x32 tiled transposes (4 weights) ----------------
struct TransArgs {
  const void* src[4];
  u16* dst[4];
  int R[4], C[4];
  int cumb[5];
};
__global__ void transpose_all(TransArgs a, const unsigned* __restrict__ xw){
  __shared__ u16 tl[32][33];
  bool isbf = detect_inline(xw);
  int b = blockIdx.x;
  int s = 0;
  while (b >= a.cumb[s + 1]) ++s;
  int lb = b - a.cumb[s];
  const void* in = a.src[s];
  u16* out = a.dst[s];
  int R = a.R[s], Cc = a.C[s];
  int ntc = Cc >> 5;
  int br = lb / ntc, bc = lb % ntc;
  int t = threadIdx.x;
#pragma unroll
  for (int i = 0; i < 4; ++i){
    int r = (t >> 5) + i * 8, c = t & 31;
    size_t idx = (size_t)(br * 32 + r) * Cc + bc * 32 + c;
    tl[r][c] = isbf ? ((const u16*)in)[idx] : f2bf(((const float*)in)[idx]);
  }
  __syncthreads();
#pragma unroll
  for (int i = 0; i < 4; ++i){
    int c = (t >> 5) + i * 8, r = t & 31;
    out[(size_t)(bc * 32 + c) * R + br * 32 + r] = tl[r][c];
  }
}

// ---------------- LN1 v2: vectorized raw reads, 16-l tiles ----------------
__global__ void ln1_pos_kernel(const void* __restrict__ xr, const void* __restrict__ posr,
                               const u16* __restrict__ g, const u16* __restrict__ b,
                               u16* __restrict__ xf, int n0){
  __shared__ u16 xs[384 * 20];
  __shared__ float ps_[64][16], pq_[64][16];
  __shared__ float mls[16], rls[16];
  bool isbf = detect_inline((const unsigned*)xr);
  const int tid = threadIdx.x;
  const int ln_ = blockIdx.x >> 6;
  const int n = n0 + ln_;
  const int l0 = (blockIdx.x & 63) << 4;
  const int cs = tid >> 2;
  const int lq = (tid & 3) << 2;
  float s[4] = {0.f, 0.f, 0.f, 0.f}, sq[4] = {0.f, 0.f, 0.f, 0.f};
#pragma unroll
  for (int it = 0; it < 6; ++it){
    int c = cs + it * 64;
    size_t base = (size_t)(n * 384 + c) * 1024 + l0 + lq;
    float v[4];
    if (isbf){
      us4 u = *(const us4*)((const u16*)xr + base);
#pragma unroll
      for (int i = 0; i < 4; ++i) v[i] = bf2f(u[i]);
    } else {
      f32x4 f = *(const f32x4*)((const float*)xr + base);
#pragma unroll
      for (int i = 0; i < 4; ++i) v[i] = f[i];
    }
    us4 o;
#pragma unroll
    for (int i = 0; i < 4; ++i){
      s[i] += v[i]; sq[i] += v[i] * v[i];
      o[i] = f2bf_fast(v[i]);
    }
    *(us4*)&xs[c * 20 + lq] = o;
  }
#pragma unroll
  for (int i = 0; i < 4; ++i){ ps_[cs][lq + i] = s[i]; pq_[cs][lq + i] = sq[i]; }
  __syncthreads();
  for (int st = 32; st >= 1; st >>= 1){
    if (cs < st){
#pragma unroll
      for (int i = 0; i < 4; ++i){
        ps_[cs][lq + i] += ps_[cs + st][lq + i];
        pq_[cs][lq + i] += pq_[cs + st][lq + i];
      }
    }
    __syncthreads();
  }
  if (tid < 16){
    float mean = ps_[0][tid] * (1.f / 384.f);
    float var = pq_[0][tid] * (1.f / 384.f) - mean * mean;
    mls[tid] = mean; rls[tid] = rsqrtf(fmaxf(var, 0.f) + 1e-5f);
  }
  __syncthreads();
  for (int idx = tid; idx < 384 * 16; idx += 256){
    int c = idx % 384, l = idx / 384;
    size_t pidx = (size_t)(l0 + l) * 384 + c;
    float pv = isbf ? bf2f(((const u16*)posr)[pidx]) : ((const float*)posr)[pidx];
    float v = (bf2f(xs[c * 20 + l]) - mls[l]) * rls[l] * bf2f(g[c]) + bf2f(b[c]) + pv;
    xf[(size_t)(ln_ * 1024 + l0 + l) * 384 + c] = f2bf_fast(v);
  }
}

// ---------------- rowwise LN over last dim of [rows][384] ----------------
__global__ void ln_row(const u16* __restrict__ in, const u16* __restrict__ g,
                       const u16* __restrict__ b, u16* __restrict__ out){
  int w = threadIdx.x >> 6, lane = threadIdx.x & 63;
  size_t row = (size_t)blockIdx.x * 4 + w;
  const u16* r = in + row * 384;
  float v[6]; float s = 0.f, sq = 0.f;
#pragma unroll
  for (int i = 0; i < 6; ++i){ v[i] = bf2f(r[lane + i * 64]); s += v[i]; sq += v[i] * v[i]; }
#pragma unroll
  for (int m = 1; m < 64; m <<= 1){ s += __shfl_xor(s, m); sq += __shfl_xor(sq, m); }
  float mean = s * (1.f / 384.f);
  float var = sq * (1.f / 384.f) - mean * mean;
  float rv = rsqrtf(fmaxf(var, 0.f) + 1e-5f);
#pragma unroll
  for (int i = 0; i < 6; ++i){
    int c = lane + i * 64;
    out[row * 384 + c] = f2bf_fast((v[i] - mean) * rv * bf2f(g[c]) + bf2f(b[c]));
  }
}

// ====== (MF*32)x(NF*32) MFMA GEMM, 2-phase double-buffered LDS, K-step=KB ======
// MODE 0: +bias   MODE 1: +bias+resid[NCHW gather, flag-aware raw]   MODE 2: +bias tanh-GELU
// MODE 3: +bias+resid2[NLC]; NCL flag-aware write (fallback)   MODE 4: qkv split-write
template<int MODE, int NF, int MF, int KB = 32>
__global__ void gemm128(const u16* __restrict__ A, const u16* __restrict__ BT,
                        const u16* __restrict__ bias, void* __restrict__ Co,
                        const void* __restrict__ resid, int M, int K, int Nn, int row0,
                        const int* __restrict__ oflag, u16* __restrict__ vt){
  (void)M;
  __shared__ u16 lsA[2][MF * 32 * KB];
  __shared__ u16 lsB[2][NF * 32 * KB];
  const int BM = MF * 32, BN = NF * 32;
  const int ntN = Nn / BN;
  int bid = blockIdx.x;
  {
    int nwg = gridDim.x;
    if ((nwg & 7) == 0){ int per = nwg >> 3; bid = (bid & 7) * per + (bid >> 3); }
  }
  const int bm = bid / ntN;
  const int bn = bid % ntN;
  const int tid = threadIdx.x;
  const int lane = tid & 63;
  const int w = tid >> 6;
  const int wr = w >> 1, wc = w & 1;
  const u16* Ab = A + (size_t)bm * BM * K;
  const u16* Bb = BT + (size_t)bn * BN * K;
  bool robf = false;
  if (MODE == 1 || MODE == 3) robf = (*oflag != 0);

  constexpr int CPR  = KB / 8;
  constexpr int NCHA = MF * 32 * CPR;
  constexpr int NCHB = NF * 32 * CPR;
  auto stage = [&](int buf, int k0){
#pragma unroll
    for (int i = 0; i < (NCHA + 255) / 256; ++i){
      int c = i * 256 + tid;
      if ((NCHA % 256 == 0) || c < NCHA){
        int row = c / CPR, cc = c % CPR;
        gload_lds16(Ab + (size_t)row * K + k0 + cc * 8,
                    (char*)(&lsA[buf][0]) + (size_t)(i * 256 + w * 64) * 16);
      }
    }
#pragma unroll
    for (int i = 0; i < (NCHB + 255) / 256; ++i){
      int c = i * 256 + tid;
      if ((NCHB % 256 == 0) || c < NCHB){
        int row = c / CPR, cc = c % CPR;
        gload_lds16(Bb + (size_t)row * K + k0 + cc * 8,
                    (char*)(&lsB[buf][0]) + (size_t)(i * 256 + w * 64) * 16);
      }
    }
  };

  f32x4 zero4 = {0.f, 0.f, 0.f, 0.f};
  f32x4 acc[MF][NF];
#pragma unroll
  for (int m = 0; m < MF; ++m)
#pragma unroll
    for (int nn = 0; nn < NF; ++nn) acc[m][nn] = zero4;
  const int kk = (lane >> 4) << 3;

  stage(0, 0);
  __syncthreads();
  int cur = 0;
  for (int k0 = 0; k0 < K; k0 += KB){
    if (k0 + KB < K) stage(cur ^ 1, k0 + KB);
#pragma unroll
    for (int ks = 0; ks < KB / 32; ++ks){
      short8 af[MF], bfr[NF];
#pragma unroll
      for (int m = 0; m < MF; ++m)
        af[m] = *(const short8*)&lsA[cur][(wr * MF * 16 + m * 16 + (lane & 15)) * KB + ks * 32 + kk];
#pragma unroll
      for (int nn = 0; nn < NF; ++nn)
        bfr[nn] = *(const short8*)&lsB[cur][(wc * NF * 16 + nn * 16 + (lane & 15)) * KB + ks * 32 + kk];
      __builtin_amdgcn_s_setprio(1);
#pragma unroll
      for (int m = 0; m < MF; ++m)
#pragma unroll
        for (int nn = 0; nn < NF; ++nn)
          acc[m][nn] = __builtin_amdgcn_mfma_f32_16x16x32_bf16(af[m], bfr[nn], acc[m][nn], 0, 0, 0);
      __builtin_amdgcn_s_setprio(0);
    }
    __syncthreads();
    cur ^= 1;
  }

#pragma unroll
  for (int m = 0; m < MF; ++m){
#pragma unroll
    for (int nn = 0; nn < NF; ++nn){
#pragma unroll
      for (int j = 0; j < 4; ++j){
        int row = bm * BM + wr * MF * 16 + m * 16 + ((lane >> 4) << 2) + j;
        int col = bn * BN + wc * NF * 16 + nn * 16 + (lane & 15);
        float v = acc[m][nn][j] + bf2f(bias[col]);
        if (MODE == 2){
          float y = 0.7978845608028654f * fmaf(0.044715f * v * v, v, v);
          v = v / (1.f + exp2f(-2.8853900817779268f * y));
        }
        if (MODE == 1){
          int rg = row0 + row;
          size_t ridx = ((size_t)((rg >> 10) * 384 + col)) * 1024 + (rg & 1023);
          v += robf ? bf2f(((const u16*)resid)[ridx]) : ((const float*)resid)[ridx];
          ((u16*)Co)[(size_t)row * Nn + col] = f2bf_fast(v);
        } else if (MODE == 3){
          int rg = row0 + row;
          v += bf2f(((const u16*)resid)[(size_t)rg * 384 + col]);
          size_t oidx = ((size_t)((rg >> 10) * 384 + col)) * 1024 + (rg & 1023);
          if (robf) ((u16*)Co)[oidx] = f2bf(v);
          else      ((float*)Co)[oidx] = v;
        } else if (MODE == 4){
          if (col < 768){
            ((u16*)Co)[(size_t)row * 768 + col] = f2bf_fast(v);
          } else {
            int vc = col - 768;
            int vh = vc / 48, vd = vc % 48;
            vt[((size_t)(((row >> 10) * 8 + vh) * 48 + vd)) * 1024 + (row & 1023)] = f2bf_fast(v);
          }
        } else {
          ((u16*)Co)[(size_t)row * Nn + col] = f2bf_fast(v);
        }
      }
    }
  }
}

#define AT_SCALE 0.14433756729740643f
#define AT_SCALE2 (0.14433756729740643f * 1.4426950408889634f)

// ---------------- attention v5 (proven best): no-max softmax, 256 thr, grid 1024 ----------------
__global__ __launch_bounds__(256, 4)
void attn5_kernel(const u16* __restrict__ qk, const u16* __restrict__ vtg,
                  const u16* __restrict__ relH, const u16* __restrict__ relW,
                  u16* __restrict__ outp){
  __shared__ u16 Pt[64 * 72];
  __shared__ u16 Kt[64 * 72];
  __shared__ u16 Vt[48 * 72];
  __shared__ float rH[511], rW[511];
  const int tid = threadIdx.x, lane = tid & 63, w = tid >> 6;
  const int d = blockIdx.x;
  const int g = ((d >> 7) << 3) | (d & 7);
  const int m_ = (d >> 3) & 15;
  const int n = g >> 3;
  const int h = g & 7;
  const int q0 = m_ << 6;
  const short8 zz = {0, 0, 0, 0, 0, 0, 0, 0};

  for (int i = tid; i < 511; i += 256){
    rH[i] = bf2f(relH[i * 8 + h]) * INV_LN2;
    rW[i] = bf2f(relW[i * 8 + h]) * INV_LN2;
  }
  const size_t baseVT = ((size_t)((n * 8 + h) * 48)) * 1024;
  const int kk = (lane >> 4) << 3;

  const size_t baseQr = ((size_t)(n * 1024 + q0 + w * 16 + (lane & 15))) * 768 + h * 48;
  short8 aQ0 = *(const short8*)&qk[baseQr + kk];
  short8 aQ1 = (kk < 16) ? *(const short8*)&qk[baseQr + 32 + kk] : zz;

  short8 kr0, kr1, vr0, vr1;
  const int k0r = tid >> 3, k0c = tid & 7;
  const int k1r = (tid + 256) >> 3;
  const int v0d = tid >> 3, v0l = tid & 7;
  const int v1d = (tid + 256) >> 3;
  auto loadKV = [&](int kt1){
    int kv0 = kt1 << 6;
    size_t bK = ((size_t)(n * 1024 + kv0)) * 768 + 384 + h * 48;
    kr0 = (k0c < 6) ? *(const short8*)&qk[bK + (size_t)k0r * 768 + k0c * 8] : zz;
    kr1 = (k0c < 6) ? *(const short8*)&qk[bK + (size_t)k1r * 768 + k0c * 8] : zz;
    vr0 = *(const short8*)&vtg[baseVT + (size_t)v0d * 1024 + kv0 + v0l * 8];
    if (tid < 128) vr1 = *(const short8*)&vtg[baseVT + (size_t)v1d * 1024 + kv0 + v0l * 8];
  };
  auto writeKV = [&](){
    *(short8*)&Kt[k0r * 72 + k0c * 8] = kr0;
    *(short8*)&Kt[k1r * 72 + k0c * 8] = kr1;
    *(short8*)&Vt[v0d * 72 + v0l * 8] = vr0;
    if (tid < 128) *(short8*)&Vt[v1d * 72 + v0l * 8] = vr1;
  };

  loadKV(0);
  writeKV();
  __syncthreads();

  float lsum[4];
  f32x4 oac[3];
  f32x4 zero4 = {0.f, 0.f, 0.f, 0.f};
#pragma unroll
  for (int j = 0; j < 4; ++j) lsum[j] = 0.f;
#pragma unroll
  for (int d3 = 0; d3 < 3; ++d3) oac[d3] = zero4;

  int qh_[4];
  float rw0_[4], rw1_[4];
#pragma unroll
  for (int j = 0; j < 4; ++j){
    int qi = q0 + w * 16 + ((lane >> 4) << 2) + j;
    qh_[j] = qi >> 5;
    int qw = qi & 31;
    rw0_[j] = rW[qw - (lane & 15) + 255];
    rw1_[j] = rW[qw - (lane & 15) + 239];
  }

  for (int kt = 0; kt < 16; ++kt){
    f32x4 sc[4];
#pragma unroll
    for (int nn = 0; nn < 4; ++nn) sc[nn] = zero4;
    __builtin_amdgcn_s_setprio(1);
#pragma unroll
    for (int nn = 0; nn < 4; ++nn){
      short8 bK0 = *(const short8*)&Kt[(nn * 16 + (lane & 15)) * 72 + kk];
      sc[nn] = __builtin_amdgcn_mfma_f32_16x16x32_bf16(aQ0, bK0, sc[nn], 0, 0, 0);
      short8 bK1 = *(const short8*)&Kt[(nn * 16 + (lane & 15)) * 72 + 32 + kk];
      sc[nn] = __builtin_amdgcn_mfma_f32_16x16x32_bf16(aQ1, bK1, sc[nn], 0, 0, 0);
    }
    __builtin_amdgcn_s_setprio(0);

    if (kt < 15) loadKV(kt + 1);

#pragma unroll
    for (int j = 0; j < 4; ++j){
      int ih = qh_[j] - (kt << 1) + 255;
      float rh0 = rH[ih], rh1 = rH[ih - 1];
      float e0 = exp2f(fmaf(sc[0][j], AT_SCALE2, rh0 + rw0_[j]));
      float e1 = exp2f(fmaf(sc[1][j], AT_SCALE2, rh0 + rw1_[j]));
      float e2 = exp2f(fmaf(sc[2][j], AT_SCALE2, rh1 + rw0_[j]));
      float e3 = exp2f(fmaf(sc[3][j], AT_SCALE2, rh1 + rw1_[j]));
      lsum[j] += (e0 + e1) + (e2 + e3);
      int prow = (w * 16 + ((lane >> 4) << 2) + j) * 72 + (lane & 15);
      Pt[prow]      = f2bf_fast(e0);
      Pt[prow + 16] = f2bf_fast(e1);
      Pt[prow + 32] = f2bf_fast(e2);
      Pt[prow + 48] = f2bf_fast(e3);
    }

    __builtin_amdgcn_s_setprio(1);
#pragma unroll
    for (int k0i = 0; k0i < 2; ++k0i){
      short8 aP = *(const short8*)&Pt[(w * 16 + (lane & 15)) * 72 + k0i * 32 + kk];
#pragma unroll
      for (int d3 = 0; d3 < 3; ++d3){
        short8 bV = *(const short8*)&Vt[(d3 * 16 + (lane & 15)) * 72 + k0i * 32 + kk];
        oac[d3] = __builtin_amdgcn_mfma_f32_16x16x32_bf16(aP, bV, oac[d3], 0, 0, 0);
      }
    }
    __builtin_amdgcn_s_setprio(0);

    if (kt < 15){
      __syncthreads();
      writeKV();
      __syncthreads();
    }
  }

#pragma unroll
  for (int j = 0; j < 4; ++j){
    float l = lsum[j];
    l += __shfl_xor(l, 1);
    l += __shfl_xor(l, 2);
    l += __shfl_xor(l, 4);
    l += __shfl_xor(l, 8);
    float rl = 1.0f / l;
    int row = q0 + w * 16 + ((lane >> 4) << 2) + j;
#pragma unroll
    for (int d3 = 0; d3 < 3; ++d3){
      int col = h * 48 + d3 * 16 + (lane & 15);
      outp[(size_t)(n * 1024 + row) * 384 + col] = f2bf_fast(oac[d3][j] * rl);
    }
  }
}

// ---------------- attention v1 (fallback path, per-n, qkv[row][1152]) ----------------
__global__ void attn_kernel(const u16* __restrict__ qkv, const u16* __restrict__ relH,
                            const u16* __restrict__ relW, u16* __restrict__ outp, int n0){
  __shared__ u16 Qt[64 * 72];
  __shared__ u16 Kt[64 * 72];
  __shared__ u16 Vt[48 * 72];
  __shared__ float rH[511], rW[511];
  const int tid = threadIdx.x, lane = tid & 63, w = tid >> 6;
  const int bid = blockIdx.x;
  const int ln_ = bid >> 7;
  const int n = n0 + ln_;
  const int h = (bid >> 4) & 7;
  const int q0 = (bid & 15) << 6;
  const short8 zz = {0, 0, 0, 0, 0, 0, 0, 0};

  for (int i = tid; i < 511; i += 256){ rH[i] = bf2f(relH[i * 8 + h]); rW[i] = bf2f(relW[i * 8 + h]); }
  const size_t baseQ = ((size_t)(ln_ * 1024 + q0)) * 1152 + h * 48;
  for (int c8 = tid; c8 < 512; c8 += 256){
    int ch = c8 >> 6, r = c8 & 63;
    short8 qv = zz;
    if (ch < 6) qv = *(const short8*)&qkv[baseQ + (size_t)r * 1152 + ch * 8];
    *(short8*)&Qt[r * 72 + ch * 8] = qv;
  }
  __syncthreads();
  const int kk = (lane >> 4) << 3;
  short8 aQ0 = *(const short8*)&Qt[(w * 16 + (lane & 15)) * 72 + kk];
  short8 aQ1 = *(const short8*)&Qt[(w * 16 + (lane & 15)) * 72 + 32 + kk];
  u16* Pt = Qt;

  float mrow[4], lrow[4];
  f32x4 oac[3];
  f32x4 zero4 = {0.f, 0.f, 0.f, 0.f};
#pragma unroll
  for (int j = 0; j < 4; ++j){ mrow[j] = -1e30f; lrow[j] = 0.f; }
#pragma unroll
  for (int d3 = 0; d3 < 3; ++d3) oac[d3] = zero4;

  int qh_[4], qw_[4];
#pragma unroll
  for (int j = 0; j < 4; ++j){
    int qi = q0 + w * 16 + ((lane >> 4) << 2) + j;
    qh_[j] = qi >> 5; qw_[j] = qi & 31;
  }

  for (int kt = 0; kt < 16; ++kt){
    int kv0 = kt << 6;
    const size_t baseKV = ((size_t)(ln_ * 1024 + kv0)) * 1152 + h * 48;
    __syncthreads();
    for (int c8 = tid; c8 < 512; c8 += 256){
      int ch = c8 >> 6, r = c8 & 63;
      short8 kv = zz;
      if (ch < 6){
        kv = *(const short8*)&qkv[baseKV + 384 + (size_t)r * 1152 + ch * 8];
        short8 vv = *(const short8*)&qkv[baseKV + 768 + (size_t)r * 1152 + ch * 8];
#pragma unroll
        for (int i = 0; i < 8; ++i) Vt[(ch * 8 + i) * 72 + r] = (u16)vv[i];
      }
      *(short8*)&Kt[r * 72 + ch * 8] = kv;
    }
    __syncthreads();

    f32x4 sc[4];
#pragma unroll
    for (int nn = 0; nn < 4; ++nn) sc[nn] = zero4;
#pragma unroll
    for (int nn = 0; nn < 4; ++nn){
      short8 bK0 = *(const short8*)&Kt[(nn * 16 + (lane & 15)) * 72 + kk];
      sc[nn] = __builtin_amdgcn_mfma_f32_16x16x32_bf16(aQ0, bK0, sc[nn], 0, 0, 0);
      short8 bK1 = *(const short8*)&Kt[(nn * 16 + (lane & 15)) * 72 + 32 + kk];
      sc[nn] = __builtin_amdgcn_mfma_f32_16x16x32_bf16(aQ1, bK1, sc[nn], 0, 0, 0);
    }

#pragma unroll
    for (int j = 0; j < 4; ++j){
      float pv[4];
      float tm = -1e30f;
#pragma unroll
      for (int nn = 0; nn < 4; ++nn){
        int kj = kv0 + nn * 16 + (lane & 15);
        float sv = sc[nn][j] * AT_SCALE + rH[qh_[j] - (kj >> 5) + 255] + rW[qw_[j] - (kj & 31) + 255];
        pv[nn] = sv;
        tm = fmaxf(tm, sv);
      }
      tm = fmaxf(tm, __shfl_xor(tm, 1));
      tm = fmaxf(tm, __shfl_xor(tm, 2));
      tm = fmaxf(tm, __shfl_xor(tm, 4));
      tm = fmaxf(tm, __shfl_xor(tm, 8));
      float mnew = fmaxf(mrow[j], tm);
      float corr = __expf(mrow[j] - mnew);
      mrow[j] = mnew;
      float ps = 0.f;
#pragma unroll
      for (int nn = 0; nn < 4; ++nn){
        float e = __expf(pv[nn] - mnew);
        ps += e;
        Pt[(w * 16 + ((lane >> 4) << 2) + j) * 72 + nn * 16 + (lane & 15)] = f2bf(e);
      }
      ps += __shfl_xor(ps, 1);
      ps += __shfl_xor(ps, 2);
      ps += __shfl_xor(ps, 4);
      ps += __shfl_xor(ps, 8);
      lrow[j] = lrow[j] * corr + ps;
#pragma unroll
      for (int d3 = 0; d3 < 3; ++d3) oac[d3][j] *= corr;
    }

#pragma unroll
    for (int k0i = 0; k0i < 2; ++k0i){
      short8 aP = *(const short8*)&Pt[(w * 16 + (lane & 15)) * 72 + k0i * 32 + kk];
#pragma unroll
      for (int d3 = 0; d3 < 3; ++d3){
        short8 bV = *(const short8*)&Vt[(d3 * 16 + (lane & 15)) * 72 + k0i * 32 + kk];
        oac[d3] = __builtin_amdgcn_mfma_f32_16x16x32_bf16(aP, bV, oac[d3], 0, 0, 0);
      }
    }
  }

#pragma unroll
  for (int d3 = 0; d3 < 3; ++d3)
#pragma unroll
    for (int j = 0; j < 4; ++j){
      int row = q0 + w * 16 + ((lane >> 4) << 2) + j;
      int col = h * 48 + d3 * 16 + (lane & 15);
      float v = oac[d3][j] / lrow[j];
      outp[(size_t)(n * 1024 + row) * 384 + col] = f2bf(v);
    }
}

// ---------------- final: out[n][c][l] = x2[n][l][c] + m2[n][l][c], flag-aware dtype ----------------
__global__ void final_add(const u16* __restrict__ x2, const u16* __restrict__ m2,
                          void* __restrict__ out, const int* __restrict__ flag){
  __shared__ float ts[32][65];
  bool isbf = (*flag != 0);
  int bid = blockIdx.x;
  int n = bid / 192;
  int rem = bid % 192;
  int c0 = (rem / 16) * 32;
  int l0 = (rem % 16) * 64;
  int t = threadIdx.x;
#pragma unroll
  for (int i = 0; i < 8; ++i){
    int lr = (t >> 5) + i * 8, cr = t & 31;
    size_t src = (size_t)(n * 1024 + l0 + lr) * 384 + c0 + cr;
    ts[cr][lr] = bf2f(x2[src]) + bf2f(m2[src]);
  }
  __syncthreads();
#pragma unroll
  for (int i = 0; i < 8; ++i){
    int cw = (t >> 6) + i * 4, lw = t & 63;
    size_t oidx = (size_t)(n * 384 + c0 + cw) * 1024 + l0 + lw;
    if (isbf) ((u16*)out)[oidx] = f2bf(ts[cw][lw]);
    else      ((float*)out)[oidx] = ts[cw][lw];
  }
}

extern "C" void kernel_launch(void* const* d_in, const int* in_sizes, int n_in,
                              void* d_out, int out_size, void* d_ws, size_t ws_size,
                              hipStream_t stream){
  (void)in_sizes; (void)n_in; (void)out_size;
  char* ws = (char*)d_ws;
  size_t off = 0;
  auto alloc = [&](size_t bytes) -> char* {
    char* p = ws + off;
    off += ((bytes + 255) & ~(size_t)255);
    return p;
  };
  // ---- common layout ----
  int* flag   = (int*)alloc(256);
  u16* wTqkv  = (u16*)alloc((size_t)1152 * 384 * 2);
  u16* wTproj = (u16*)alloc((size_t)384 * 384 * 2);
  u16* wTm1   = (u16*)alloc((size_t)1536 * 384 * 2);
  u16* wTm2   = (u16*)alloc((size_t)384 * 1536 * 2);
  u16* bqkvc  = (u16*)alloc(1152 * 2);
  u16* bprojc = (u16*)alloc(384 * 2);
  u16* ln1gc  = (u16*)alloc(384 * 2);
  u16* ln1bc  = (u16*)alloc(384 * 2);
  u16* ln2gc  = (u16*)alloc(384 * 2);
  u16* ln2bc  = (u16*)alloc(384 * 2);
  u16* bm1c   = (u16*)alloc(1536 * 2);
  u16* bm2c   = (u16*)alloc(384 * 2);
  u16* relHc  = (u16*)alloc(4088 * 2);
  u16* relWc  = (u16*)alloc(4088 * 2);
  u16* x2     = (u16*)alloc((size_t)8192 * 384 * 2);
  size_t off_common = off;

  char* BIG1 = alloc((size_t)8192 * 384 * 2);           // 6.29 MB
  char* BIG2 = alloc((size_t)8192 * 1152 * 2);          // 18.87 MB
  bool big = (off <= ws_size);
  char* BIG3 = alloc((size_t)8192 * 1536 * 2 - (size_t)8192 * 1152 * 2);
  char* BIG4 = alloc((size_t)8192 * 384 * 2);
  bool huge = (off <= ws_size);
  (void)BIG3;

  // ---- fused canonicalization (small inputs only; x/pos consumed raw) ----
  {
    ConvArgs a;
    const int srcidx[10] = {3, 5, 6, 7, 8, 9, 11, 13, 14, 15};
    u16* dsts[10] = {bqkvc, bprojc, ln1gc, ln1bc, ln2gc, ln2bc, bm1c, bm2c, relHc, relWc};
    const int n4s[10] = {288, 96, 96, 96, 96, 96, 384, 96, 1022, 1022};
    int c = 0;
    for (int i = 0; i < 10; ++i){
      a.src[i] = d_in[srcidx[i]];
      a.dst[i] = dsts[i];
      a.cum[i] = c;
      c += n4s[i];
    }
    a.cum[10] = c; a.cum[11] = c; a.cum[12] = c;
    a.src[10] = a.src[11] = nullptr; a.dst[10] = a.dst[11] = nullptr;
    convert_all<<<dim3(16), 256, 0, stream>>>(a, (const unsigned*)d_in[0], flag);
  }
  {
    TransArgs t;
    t.src[0] = d_in[2];  t.dst[0] = wTqkv;  t.R[0] = 384;  t.C[0] = 1152;
    t.src[1] = d_in[4];  t.dst[1] = wTproj; t.R[1] = 384;  t.C[1] = 384;
    t.src[2] = d_in[10]; t.dst[2] = wTm1;   t.R[2] = 384;  t.C[2] = 1536;
    t.src[3] = d_in[12]; t.dst[3] = wTm2;   t.R[3] = 1536; t.C[3] = 384;
    t.cumb[0] = 0; t.cumb[1] = 432; t.cumb[2] = 576; t.cumb[3] = 1152; t.cumb[4] = 1728;
    transpose_all<<<dim3(1728), 256, 0, stream>>>(t, (const unsigned*)d_in[0]);
  }

  if (big){
    u16* xf    = (u16*)BIG1;
    u16* attno = (u16*)BIG1;
    u16* y2    = (u16*)BIG1;
    u16* qkbuf = (u16*)BIG2;                               // [8192][768]
    u16* VT    = (u16*)(BIG2 + (size_t)8192 * 768 * 2);    // [8][8][48][1024]

    ln1_pos_kernel<<<dim3(512), 256, 0, stream>>>(d_in[0], d_in[1], ln1gc, ln1bc, xf, 0);
    gemm128<4, 4, 4><<<dim3(576), 256, 0, stream>>>(xf, wTqkv, bqkvc, qkbuf, nullptr, 8192, 384, 1152, 0, flag, VT);
    attn5_kernel<<<dim3(1024), 256, 0, stream>>>(qkbuf, VT, relHc, relWc, attno);
    gemm128<1, 3, 2><<<dim3(512), 256, 0, stream>>>(attno, wTproj, bprojc, x2, d_in[0], 8192, 384, 384, 0, flag, nullptr);
    ln_row<<<dim3(2048), 256, 0, stream>>>(x2, ln2gc, ln2bc, y2);
    if (huge){
      u16* m1 = (u16*)BIG2;
      u16* m2 = (u16*)BIG4;
      gemm128<2, 4, 4><<<dim3(768), 256, 0, stream>>>(y2, wTm1, bm1c, m1, nullptr, 8192, 384, 1536, 0, flag, nullptr);
      gemm128<0, 3, 2><<<dim3(512), 256, 0, stream>>>(m1, wTm2, bm2c, m2, nullptr, 8192, 1536, 384, 0, flag, nullptr);
      final_add<<<dim3(1536), 256, 0, stream>>>(x2, m2, d_out, flag);
    } else {
      u16* m1h = (u16*)BIG2;
      u16* m2  = (u16*)(BIG2 + (size_t)4096 * 1536 * 2);
      for (int hf = 0; hf < 2; ++hf){
        gemm128<2, 4, 4><<<dim3(384), 256, 0, stream>>>(y2 + (size_t)hf * 4096 * 384, wTm1, bm1c, m1h,
                                                        nullptr, 4096, 384, 1536, 0, flag, nullptr);
        gemm128<0, 3, 2><<<dim3(256), 256, 0, stream>>>(m1h, wTm2, bm2c, m2 + (size_t)hf * 4096 * 384,
                                                        nullptr, 4096, 1536, 384, 0, flag, nullptr);
      }
      final_add<<<dim3(1536), 256, 0, stream>>>(x2, m2, d_out, flag);
    }
  } else {
    // fallback: proven chunked path
    off = off_common;
    char* S = alloc((size_t)3932160);
    u16* xf_n  = (u16*)S;
    u16* qkv_n = (u16*)(S + 786432);
    u16* y2c   = (u16*)S;
    u16* m1c   = (u16*)(S + 786432);
    u16* attno = (u16*)d_out;

    for (int n = 0; n < 8; ++n){
      ln1_pos_kernel<<<dim3(64), 256, 0, stream>>>(d_in[0], d_in[1], ln1gc, ln1bc, xf_n, n);
      gemm128<0, 4, 4><<<dim3(72), 256, 0, stream>>>(xf_n, wTqkv, bqkvc, qkv_n, nullptr, 1024, 384, 1152, 0, flag, nullptr);
      attn_kernel<<<dim3(128), 256, 0, stream>>>(qkv_n, relHc, relWc, attno, n);
    }
    gemm128<1, 4, 4><<<dim3(192), 256, 0, stream>>>(attno, wTproj, bprojc, x2, d_in[0], 8192, 384, 384, 0, flag, nullptr);
    for (int c = 0; c < 8; ++c){
      ln_row<<<dim3(256), 256, 0, stream>>>(x2 + (size_t)c * 1024 * 384, ln2gc, ln2bc, y2c);
      gemm128<2, 4, 4><<<dim3(96), 256, 0, stream>>>(y2c, wTm1, bm1c, m1c, nullptr, 1024, 384, 1536, 0, flag, nullptr);
      gemm128<3, 4, 4><<<dim3(24), 256, 0, stream>>>(m1c, wTm2, bm2c, d_out, x2, 1024, 1536, 384, c * 1024, flag, nullptr);
    }
  }
}